// Round 1
// baseline (328.890 us; speedup 1.0000x reference)
//
#include <hip/hip_runtime.h>
#include <stdint.h>

// ---------------------------------------------------------------------------
// PointWiseGate: grid_sample gather -> concat -> conv1x1(512->256) -> BN+ReLU
//                -> spatial gate (sa 64ch max+sigmoid) -> channel gate
//                (ca1 64 relu -> ca2 256, max over N, sigmoid) -> out (B,256,N) fp32
//
// Strategy: bf16 MFMA (16x16x32) for all GEMM-shaped compute, point-major
// (B,N,C) bf16 intermediate layouts so both MFMA operands are K-contiguous.
//
// ws layout (bytes):
//   [0,          67108864)  XT   (B,N,512) bf16   ; Hg (B,N,64) bf16 aliases base after GEMM1
//   [67108864,   88080384)  imgT (B,H,W,256) bf16 ; dead after gather
//   [67108864,  100663296)  Y    (B,N,256) bf16   ; overlaps imgT lifetime-disjoint
//   [100663296, ...]        WfB/saB/ca1B/ca2B bf16 weights, BN buckets, scale/shift,
//                           camax (uint keys), channel gate
// ---------------------------------------------------------------------------

typedef __attribute__((ext_vector_type(8))) short bf16x8;
typedef __attribute__((ext_vector_type(4))) float f32x4;

#define B_ 4
#define N_ 16384
#define H_ 64
#define W_ 160
#define HW_ (H_ * W_)
#define K_ 512

__device__ __forceinline__ float bf2f(unsigned short u) {
    union { unsigned int i; float f; } c; c.i = ((unsigned int)u) << 16; return c.f;
}
__device__ __forceinline__ unsigned short f2bf(float f) {
    union { float f; unsigned int i; } c; c.f = f;
    unsigned int u = c.i;
    return (unsigned short)((u + 0x7FFFu + ((u >> 16) & 1u)) >> 16);
}
// monotonic float->uint key for atomicMax over signed floats
__device__ __forceinline__ unsigned int fkey(float f) {
    union { float f; unsigned int u; int i; } c; c.f = f;
    return (c.i < 0) ? ~c.u : (c.u | 0x80000000u);
}
__device__ __forceinline__ float funkey(unsigned int k) {
    union { unsigned int u; float f; } c;
    c.u = (k & 0x80000000u) ? (k & 0x7FFFFFFFu) : ~k;
    return c.f;
}

// ---- init accumulators (ws is re-poisoned to 0xAA before every timed launch)
__global__ void k_init(float* buckets, unsigned int* camax) {
    int t = threadIdx.x;
    for (int i = t; i < 16 * 512; i += 256) buckets[i] = 0.f;
    for (int i = t; i < 1024; i += 256) camax[i] = 0u;  // key(-inf) < key(any finite)
}

// ---- convert all weights to bf16
__global__ void k_wcvt(const float* __restrict__ fw, const float* __restrict__ saw,
                       const float* __restrict__ c1w, const float* __restrict__ c2w,
                       unsigned short* WfB, unsigned short* saB,
                       unsigned short* ca1B, unsigned short* ca2B) {
    int i = blockIdx.x * 256 + threadIdx.x;
    if (i < 131072) WfB[i] = f2bf(fw[i]);
    else if (i < 147456) saB[i - 131072] = f2bf(saw[i - 131072]);
    else if (i < 163840) ca1B[i - 147456] = f2bf(c1w[i - 147456]);
    else if (i < 180224) ca2B[i - 163840] = f2bf(c2w[i - 163840]);
}

// ---- img (B,256,H*W) fp32 -> imgT (B,H*W,256) bf16   [64x64 LDS tile transpose]
__global__ __launch_bounds__(256) void k_imgt(const float* __restrict__ img,
                                              unsigned short* __restrict__ imgT) {
    __shared__ __align__(16) unsigned short tile[64 * 72];  // [c][hw], +8 pad
    int t = threadIdx.x;
    int hw0 = blockIdx.x * 64, c0 = blockIdx.y * 64, b = blockIdx.z;
    const float* src = img + ((size_t)b * 256 + c0) * HW_ + hw0;
    int sub = (t & 15) * 4, grp = t >> 4;
#pragma unroll
    for (int it = 0; it < 4; ++it) {
        int cl = grp + it * 16;
        float4 v = *(const float4*)(src + (size_t)cl * HW_ + sub);
        ushort4 o;
        o.x = f2bf(v.x); o.y = f2bf(v.y); o.z = f2bf(v.z); o.w = f2bf(v.w);
        *(ushort4*)(tile + cl * 72 + sub) = o;
    }
    __syncthreads();
    unsigned short* dst = imgT + ((size_t)b * HW_ + hw0) * 256 + c0;
#pragma unroll
    for (int it = 0; it < 4; ++it) {
        int hwl = grp + it * 16;
        ushort4 o;
        o.x = tile[(sub + 0) * 72 + hwl];
        o.y = tile[(sub + 1) * 72 + hwl];
        o.z = tile[(sub + 2) * 72 + hwl];
        o.w = tile[(sub + 3) * 72 + hwl];
        *(ushort4*)(dst + (size_t)hwl * 256 + sub) = o;
    }
}

// ---- pts_feats (B,256,N) fp32 -> XT[b][n][256+c] bf16
__global__ __launch_bounds__(256) void k_ptst(const float* __restrict__ pts,
                                              unsigned short* __restrict__ XT) {
    __shared__ __align__(16) unsigned short tile[64 * 72];
    int t = threadIdx.x;
    int n0 = blockIdx.x * 64, c0 = blockIdx.y * 64, b = blockIdx.z;
    const float* src = pts + ((size_t)b * 256 + c0) * N_ + n0;
    int sub = (t & 15) * 4, grp = t >> 4;
#pragma unroll
    for (int it = 0; it < 4; ++it) {
        int cl = grp + it * 16;
        float4 v = *(const float4*)(src + (size_t)cl * N_ + sub);
        ushort4 o;
        o.x = f2bf(v.x); o.y = f2bf(v.y); o.z = f2bf(v.z); o.w = f2bf(v.w);
        *(ushort4*)(tile + cl * 72 + sub) = o;
    }
    __syncthreads();
    unsigned short* dst = XT + ((size_t)b * N_ + n0) * K_ + 256 + c0;
#pragma unroll
    for (int it = 0; it < 4; ++it) {
        int nl = grp + it * 16;
        ushort4 o;
        o.x = tile[(sub + 0) * 72 + nl];
        o.y = tile[(sub + 1) * 72 + nl];
        o.z = tile[(sub + 2) * 72 + nl];
        o.w = tile[(sub + 3) * 72 + nl];
        *(ushort4*)(dst + (size_t)nl * K_ + sub) = o;
    }
}

// ---- bilinear grid_sample: imgT gather -> XT[b][n][0..256) bf16
// wave = 1 point, lanes cover 256 channels via ushort4 (4x 512B contiguous corners)
__global__ __launch_bounds__(256) void k_gather(const float* __restrict__ pim,
                                                const unsigned short* __restrict__ imgT,
                                                unsigned short* __restrict__ XT) {
    int t = threadIdx.x;
    int w = t >> 6, lane = t & 63;
    int p0 = blockIdx.x * 16 + w * 4;
    int c = lane * 4;
    for (int pp = 0; pp < 4; ++pp) {
        int p = p0 + pp;
        int b = p >> 14;
        float gx = pim[(size_t)p * 2 + 0];
        float gy = pim[(size_t)p * 2 + 1];
        // torch align_corners=False: x = ((gx+1)*W - 1)/2
        float x = (gx + 1.0f) * (0.5f * W_) - 0.5f;
        float y = (gy + 1.0f) * (0.5f * H_) - 0.5f;
        float xf = floorf(x), yf = floorf(y);
        float wx1 = x - xf, wx0 = 1.0f - wx1;
        float wy1 = y - yf, wy0 = 1.0f - wy1;
        int x0 = (int)xf, y0 = (int)yf;
        int x1 = x0 + 1, y1 = y0 + 1;
        float vx0 = (x0 >= 0 && x0 < W_) ? 1.f : 0.f;
        float vx1 = (x1 >= 0 && x1 < W_) ? 1.f : 0.f;
        float vy0 = (y0 >= 0 && y0 < H_) ? 1.f : 0.f;
        float vy1 = (y1 >= 0 && y1 < H_) ? 1.f : 0.f;
        int cx0 = min(max(x0, 0), W_ - 1), cx1 = min(max(x1, 0), W_ - 1);
        int cy0 = min(max(y0, 0), H_ - 1), cy1 = min(max(y1, 0), H_ - 1);
        float w00 = wx0 * wy0 * vx0 * vy0;
        float w10 = wx1 * wy0 * vx1 * vy0;
        float w01 = wx0 * wy1 * vx0 * vy1;
        float w11 = wx1 * wy1 * vx1 * vy1;
        const unsigned short* base = imgT + (size_t)b * HW_ * 256;
        ushort4 a00 = *(const ushort4*)(base + ((size_t)cy0 * W_ + cx0) * 256 + c);
        ushort4 a10 = *(const ushort4*)(base + ((size_t)cy0 * W_ + cx1) * 256 + c);
        ushort4 a01 = *(const ushort4*)(base + ((size_t)cy1 * W_ + cx0) * 256 + c);
        ushort4 a11 = *(const ushort4*)(base + ((size_t)cy1 * W_ + cx1) * 256 + c);
        ushort4 o;
        o.x = f2bf(w00 * bf2f(a00.x) + w10 * bf2f(a10.x) + w01 * bf2f(a01.x) + w11 * bf2f(a11.x));
        o.y = f2bf(w00 * bf2f(a00.y) + w10 * bf2f(a10.y) + w01 * bf2f(a01.y) + w11 * bf2f(a11.y));
        o.z = f2bf(w00 * bf2f(a00.z) + w10 * bf2f(a10.z) + w01 * bf2f(a01.z) + w11 * bf2f(a11.z));
        o.w = f2bf(w00 * bf2f(a00.w) + w10 * bf2f(a10.w) + w01 * bf2f(a01.w) + w11 * bf2f(a11.w));
        *(ushort4*)(XT + (size_t)p * K_ + c) = o;
    }
}

// ---- GEMM1: Y[b][n][m] = sum_k Wf[m][k]*XT[b][n][k] + bias[m]   (bf16 MFMA 128x128 tile)
__global__ __launch_bounds__(256, 2) void k_gemm1(const unsigned short* __restrict__ WfB,
                                                  const unsigned short* __restrict__ XT,
                                                  const float* __restrict__ fb,
                                                  unsigned short* __restrict__ Y) {
    __shared__ __align__(16) unsigned short At[128 * 32];
    __shared__ __align__(16) unsigned short Bt[128 * 32];
    __shared__ float biasS[128];
    int t = threadIdx.x;
    int n0 = blockIdx.x * 128, m0 = blockIdx.y * 128, b = blockIdx.z;
    if (t < 128) biasS[t] = fb[m0 + t];
    const unsigned short* Xb = XT + (size_t)b * N_ * K_;
    int w = t >> 6, lane = t & 63, quad = lane >> 4, l15 = lane & 15;
    int wm = w >> 1, wn = w & 1;
    int srow = t >> 2, skoff = (t & 3) * 8;
    const f32x4 fzero = {0.f, 0.f, 0.f, 0.f};
    f32x4 acc[4][4];
#pragma unroll
    for (int i = 0; i < 4; ++i)
#pragma unroll
        for (int j = 0; j < 4; ++j) acc[i][j] = fzero;
    for (int kt = 0; kt < 16; ++kt) {
        int k0 = kt * 32;
        __syncthreads();
#pragma unroll
        for (int r = 0; r < 2; ++r) {
            int row = srow + r * 64;
            *(uint4*)(At + row * 32 + skoff) =
                *(const uint4*)(WfB + (size_t)(m0 + row) * K_ + k0 + skoff);
            *(uint4*)(Bt + row * 32 + skoff) =
                *(const uint4*)(Xb + (size_t)(n0 + row) * K_ + k0 + skoff);
        }
        __syncthreads();
        bf16x8 af[4], bv[4];
#pragma unroll
        for (int i = 0; i < 4; ++i) {
            af[i] = *(const bf16x8*)(At + (wm * 64 + i * 16 + l15) * 32 + quad * 8);
            bv[i] = *(const bf16x8*)(Bt + (wn * 64 + i * 16 + l15) * 32 + quad * 8);
        }
#pragma unroll
        for (int i = 0; i < 4; ++i)
#pragma unroll
            for (int j = 0; j < 4; ++j)
                acc[i][j] = __builtin_amdgcn_mfma_f32_16x16x32_bf16(af[i], bv[j], acc[i][j], 0, 0, 0);
    }
    size_t Yb = (size_t)b * N_ * 256;
#pragma unroll
    for (int i = 0; i < 4; ++i) {
        int mloc = wm * 64 + i * 16 + quad * 4;
        float b0 = biasS[mloc + 0], b1 = biasS[mloc + 1];
        float b2 = biasS[mloc + 2], b3 = biasS[mloc + 3];
#pragma unroll
        for (int j = 0; j < 4; ++j) {
            int n = n0 + wn * 64 + j * 16 + l15;
            ushort4 o;
            o.x = f2bf(acc[i][j][0] + b0);
            o.y = f2bf(acc[i][j][1] + b1);
            o.z = f2bf(acc[i][j][2] + b2);
            o.w = f2bf(acc[i][j][3] + b3);
            *(ushort4*)(Y + Yb + (size_t)n * 256 + m0 + mloc) = o;
        }
    }
}

// ---- BN statistics: per-channel sum / sumsq over (B,N) into 16 buckets
__global__ __launch_bounds__(256) void k_bnstats(const unsigned short* __restrict__ Y,
                                                 float* __restrict__ buckets) {
    __shared__ float red[4][32][16];
    int t = threadIdx.x;
    int lane = t & 63, w = t >> 6;
    int mc = t & 31;  // 8-channel chunk
    int rs = t >> 5;  // row slot 0..7
    int rows0 = blockIdx.x * 64;
    float s[8] = {0, 0, 0, 0, 0, 0, 0, 0}, q[8] = {0, 0, 0, 0, 0, 0, 0, 0};
    for (int pass = 0; pass < 8; ++pass) {
        int row = rows0 + rs + pass * 8;
        uint4 v = *(const uint4*)(Y + (size_t)row * 256 + mc * 8);
        const unsigned short* us = (const unsigned short*)&v;
#pragma unroll
        for (int e = 0; e < 8; ++e) {
            float f = bf2f(us[e]);
            s[e] += f;
            q[e] += f * f;
        }
    }
#pragma unroll
    for (int e = 0; e < 8; ++e) {
        s[e] += __shfl_xor(s[e], 32, 64);
        q[e] += __shfl_xor(q[e], 32, 64);
    }
    if (lane < 32) {
#pragma unroll
        for (int e = 0; e < 8; ++e) {
            red[w][lane][e] = s[e];
            red[w][lane][8 + e] = q[e];
        }
    }
    __syncthreads();
    int m = t, grp = m >> 3, e = m & 7;
    float fs = red[0][grp][e] + red[1][grp][e] + red[2][grp][e] + red[3][grp][e];
    float fq = red[0][grp][8 + e] + red[1][grp][8 + e] + red[2][grp][8 + e] + red[3][grp][8 + e];
    float* bk = buckets + (size_t)(blockIdx.x & 15) * 512;
    atomicAdd(bk + m, fs);
    atomicAdd(bk + 256 + m, fq);
}

// ---- finalize BN: scale/shift per channel
__global__ void k_bnfin(const float* buckets, const float* gamma, const float* beta, float* ss) {
    int m = threadIdx.x;
    float s = 0.f, q = 0.f;
    for (int bk = 0; bk < 16; ++bk) {
        s += buckets[bk * 512 + m];
        q += buckets[bk * 512 + 256 + m];
    }
    const float inv = 1.0f / (float)(B_ * N_);
    float mean = s * inv;
    float var = q * inv - mean * mean;
    float sc = gamma[m] * rsqrtf(var + 1e-5f);
    ss[m] = sc;
    ss[256 + m] = beta[m] - mean * sc;
}

// ---- apply BN + ReLU in place on Y (point-major)
__global__ __launch_bounds__(256) void k_bnapply(unsigned short* __restrict__ Y,
                                                 const float* __restrict__ ss) {
    __shared__ float sc[256], sh[256];
    int t = threadIdx.x;
    sc[t] = ss[t];
    sh[t] = ss[256 + t];
    __syncthreads();
    size_t idx = ((size_t)blockIdx.x * 256 + t) * 8;
    int mb = (int)(idx & 255);
    uint4 v = *(const uint4*)(Y + idx);
    unsigned short* us = (unsigned short*)&v;
#pragma unroll
    for (int e = 0; e < 8; ++e) {
        float f = bf2f(us[e]) * sc[mb + e] + sh[mb + e];
        us[e] = f2bf(fmaxf(f, 0.f));
    }
    *(uint4*)(Y + idx) = v;
}

// ---- spatial attention: S = sa_w @ fusion^T, gate = sigmoid(max_j), F *= gate (in place)
// MFMA flipped: A = fusion points (M-dim), B = sa_w rows (K-contig) -> D[pt][j]
__global__ __launch_bounds__(256, 2) void k_sa(unsigned short* __restrict__ F,
                                               const unsigned short* __restrict__ saB,
                                               const float* __restrict__ sab) {
    __shared__ __align__(16) unsigned short WS[64 * 264];  // sa_w 64x256, rows padded
    __shared__ __align__(16) unsigned short At[128 * 32];
    __shared__ float sbias[64];
    __shared__ float sp[128];
    int t = threadIdx.x;
    for (int idx = t * 8; idx < 64 * 256; idx += 2048) {
        int r = idx >> 8, c = idx & 255;
        *(uint4*)(WS + r * 264 + c) = *(const uint4*)(saB + r * 256 + c);
    }
    if (t < 64) sbias[t] = sab[t];
    size_t pts0 = (size_t)blockIdx.x * 128;
    int w = t >> 6, lane = t & 63, quad = lane >> 4, l15 = lane & 15;
    int srow = t >> 2, skoff = (t & 3) * 8;
    const f32x4 fzero = {0.f, 0.f, 0.f, 0.f};
    f32x4 acc[2][4];
#pragma unroll
    for (int i = 0; i < 2; ++i)
#pragma unroll
        for (int j = 0; j < 4; ++j) acc[i][j] = fzero;
    for (int kt = 0; kt < 8; ++kt) {
        int k0 = kt * 32;
        __syncthreads();
#pragma unroll
        for (int r = 0; r < 2; ++r) {
            int row = srow + r * 64;
            *(uint4*)(At + row * 32 + skoff) =
                *(const uint4*)(F + (pts0 + row) * 256 + k0 + skoff);
        }
        __syncthreads();
        bf16x8 af[2], bv[4];
#pragma unroll
        for (int i = 0; i < 2; ++i)
            af[i] = *(const bf16x8*)(At + (w * 32 + i * 16 + l15) * 32 + quad * 8);
#pragma unroll
        for (int jt = 0; jt < 4; ++jt)
            bv[jt] = *(const bf16x8*)(WS + (jt * 16 + l15) * 264 + k0 + quad * 8);
#pragma unroll
        for (int i = 0; i < 2; ++i)
#pragma unroll
            for (int jt = 0; jt < 4; ++jt)
                acc[i][jt] = __builtin_amdgcn_mfma_f32_16x16x32_bf16(af[i], bv[jt], acc[i][jt], 0, 0, 0);
    }
    float sb[4];
#pragma unroll
    for (int jt = 0; jt < 4; ++jt) sb[jt] = sbias[jt * 16 + l15];
#pragma unroll
    for (int i = 0; i < 2; ++i) {
#pragma unroll
        for (int r = 0; r < 4; ++r) {
            float v = acc[i][0][r] + sb[0];
            v = fmaxf(v, acc[i][1][r] + sb[1]);
            v = fmaxf(v, acc[i][2][r] + sb[2]);
            v = fmaxf(v, acc[i][3][r] + sb[3]);
#pragma unroll
            for (int d = 1; d < 16; d <<= 1) v = fmaxf(v, __shfl_xor(v, d, 64));
            if (l15 == 0) sp[w * 32 + i * 16 + quad * 4 + r] = 1.0f / (1.0f + __expf(-v));
        }
    }
    __syncthreads();
    for (int idx = t * 8; idx < 128 * 256; idx += 2048) {
        int row = idx >> 8;
        float s = sp[row];
        unsigned short* ptr = F + (pts0 + row) * 256 + (idx & 255);
        uint4 v = *(const uint4*)ptr;
        unsigned short* us = (unsigned short*)&v;
#pragma unroll
        for (int e = 0; e < 8; ++e) us[e] = f2bf(bf2f(us[e]) * s);
        *(uint4*)ptr = v;
    }
}

// ---- ca1: Hg[b][n][h] = relu(ca1_w @ fusionG^T + b1)   (same structure as k_sa)
__global__ __launch_bounds__(256, 2) void k_ca1(const unsigned short* __restrict__ F,
                                                const unsigned short* __restrict__ c1B,
                                                const float* __restrict__ c1b,
                                                unsigned short* __restrict__ Hg) {
    __shared__ __align__(16) unsigned short WS[64 * 264];
    __shared__ __align__(16) unsigned short At[128 * 32];
    __shared__ __align__(16) unsigned short Ht[128 * 72];
    __shared__ float cbias[64];
    int t = threadIdx.x;
    for (int idx = t * 8; idx < 64 * 256; idx += 2048) {
        int r = idx >> 8, c = idx & 255;
        *(uint4*)(WS + r * 264 + c) = *(const uint4*)(c1B + r * 256 + c);
    }
    if (t < 64) cbias[t] = c1b[t];
    size_t pts0 = (size_t)blockIdx.x * 128;
    int w = t >> 6, lane = t & 63, quad = lane >> 4, l15 = lane & 15;
    int srow = t >> 2, skoff = (t & 3) * 8;
    const f32x4 fzero = {0.f, 0.f, 0.f, 0.f};
    f32x4 acc[2][4];
#pragma unroll
    for (int i = 0; i < 2; ++i)
#pragma unroll
        for (int j = 0; j < 4; ++j) acc[i][j] = fzero;
    for (int kt = 0; kt < 8; ++kt) {
        int k0 = kt * 32;
        __syncthreads();
#pragma unroll
        for (int r = 0; r < 2; ++r) {
            int row = srow + r * 64;
            *(uint4*)(At + row * 32 + skoff) =
                *(const uint4*)(F + (pts0 + row) * 256 + k0 + skoff);
        }
        __syncthreads();
        bf16x8 af[2], bv[4];
#pragma unroll
        for (int i = 0; i < 2; ++i)
            af[i] = *(const bf16x8*)(At + (w * 32 + i * 16 + l15) * 32 + quad * 8);
#pragma unroll
        for (int jt = 0; jt < 4; ++jt)
            bv[jt] = *(const bf16x8*)(WS + (jt * 16 + l15) * 264 + k0 + quad * 8);
#pragma unroll
        for (int i = 0; i < 2; ++i)
#pragma unroll
            for (int jt = 0; jt < 4; ++jt)
                acc[i][jt] = __builtin_amdgcn_mfma_f32_16x16x32_bf16(af[i], bv[jt], acc[i][jt], 0, 0, 0);
    }
#pragma unroll
    for (int i = 0; i < 2; ++i)
#pragma unroll
        for (int jt = 0; jt < 4; ++jt) {
            int j = jt * 16 + l15;
            float bb = cbias[j];
#pragma unroll
            for (int r = 0; r < 4; ++r) {
                int pt = w * 32 + i * 16 + quad * 4 + r;
                Ht[pt * 72 + j] = f2bf(fmaxf(acc[i][jt][r] + bb, 0.f));
            }
        }
    __syncthreads();
    for (int idx = t * 8; idx < 128 * 64; idx += 2048) {
        int row = idx >> 6, c = idx & 63;
        *(uint4*)(Hg + (pts0 + row) * 64 + c) = *(const uint4*)(Ht + row * 72 + c);
    }
}

// ---- ca2: C2[pt][m2] = ca2_w @ H^T ; atomicMax over points per (b, m2)
__global__ __launch_bounds__(256, 2) void k_ca2(const unsigned short* __restrict__ Hg,
                                                const unsigned short* __restrict__ c2B,
                                                unsigned int* __restrict__ camax) {
    __shared__ __align__(16) unsigned short W2[256 * 72];  // ca2_w 256x64, padded
    __shared__ __align__(16) unsigned short At[64 * 72];
    int t = threadIdx.x;
    for (int idx = t * 8; idx < 256 * 64; idx += 2048) {
        int r = idx >> 6, c = idx & 63;
        *(uint4*)(W2 + r * 72 + c) = *(const uint4*)(c2B + r * 64 + c);
    }
    size_t pts0 = (size_t)blockIdx.x * 64;
    int b = (int)(pts0 >> 14);
    for (int idx = t * 8; idx < 64 * 64; idx += 2048) {
        int r = idx >> 6, c = idx & 63;
        *(uint4*)(At + r * 72 + c) = *(const uint4*)(Hg + (pts0 + r) * 64 + c);
    }
    __syncthreads();
    int w = t >> 6, lane = t & 63, quad = lane >> 4, l15 = lane & 15;
    const f32x4 fzero = {0.f, 0.f, 0.f, 0.f};
    f32x4 acc[4][4];
#pragma unroll
    for (int i = 0; i < 4; ++i)
#pragma unroll
        for (int j = 0; j < 4; ++j) acc[i][j] = fzero;
#pragma unroll
    for (int kk = 0; kk < 2; ++kk) {
        bf16x8 af[4], bv[4];
#pragma unroll
        for (int i = 0; i < 4; ++i)
            af[i] = *(const bf16x8*)(At + (i * 16 + l15) * 72 + kk * 32 + quad * 8);
#pragma unroll
        for (int mt = 0; mt < 4; ++mt)
            bv[mt] = *(const bf16x8*)(W2 + (w * 64 + mt * 16 + l15) * 72 + kk * 32 + quad * 8);
#pragma unroll
        for (int i = 0; i < 4; ++i)
#pragma unroll
            for (int mt = 0; mt < 4; ++mt)
                acc[i][mt] = __builtin_amdgcn_mfma_f32_16x16x32_bf16(af[i], bv[mt], acc[i][mt], 0, 0, 0);
    }
#pragma unroll
    for (int mt = 0; mt < 4; ++mt) {
        float v = acc[0][mt][0];
#pragma unroll
        for (int i = 0; i < 4; ++i)
#pragma unroll
            for (int r = 0; r < 4; ++r) v = fmaxf(v, acc[i][mt][r]);
        v = fmaxf(v, __shfl_xor(v, 16, 64));
        v = fmaxf(v, __shfl_xor(v, 32, 64));
        if (quad == 0) atomicMax(camax + b * 256 + w * 64 + mt * 16 + l15, fkey(v));
    }
}

// ---- channel gate: sigmoid(max + ca2_b)
__global__ void k_chfin(const unsigned int* camax, const float* c2b, float* channel) {
    int b = blockIdx.x, m = threadIdx.x;
    float v = funkey(camax[b * 256 + m]) + c2b[m];
    channel[b * 256 + m] = 1.0f / (1.0f + __expf(-v));
}

// ---- out[b][m][n] = channel[b][m] * F[b][n][m]  (64x64 tile transpose, fp32 out)
__global__ __launch_bounds__(256) void k_out(const unsigned short* __restrict__ F,
                                             const float* __restrict__ channel,
                                             float* __restrict__ out) {
    __shared__ __align__(16) unsigned short tile[64 * 72];  // [n][m] padded
    __shared__ float ch[64];
    int t = threadIdx.x;
    int n0 = blockIdx.x * 64, m0 = blockIdx.y * 64, b = blockIdx.z;
    if (t < 64) ch[t] = channel[b * 256 + m0 + t];
    int sub = (t & 15) * 4, grp = t >> 4;
    const unsigned short* src = F + (size_t)b * N_ * 256;
#pragma unroll
    for (int it = 0; it < 4; ++it) {
        int nl = grp + it * 16;
        ushort4 v = *(const ushort4*)(src + (size_t)(n0 + nl) * 256 + m0 + sub);
        *(ushort4*)(tile + nl * 72 + sub) = v;
    }
    __syncthreads();
    float* dst = out + ((size_t)b * 256 + m0) * N_ + n0;
#pragma unroll
    for (int it = 0; it < 4; ++it) {
        int ml = grp + it * 16;
        float g = ch[ml];
        float4 o;
        o.x = bf2f(tile[(sub + 0) * 72 + ml]) * g;
        o.y = bf2f(tile[(sub + 1) * 72 + ml]) * g;
        o.z = bf2f(tile[(sub + 2) * 72 + ml]) * g;
        o.w = bf2f(tile[(sub + 3) * 72 + ml]) * g;
        *(float4*)(dst + (size_t)ml * N_ + sub) = o;
    }
}

extern "C" void kernel_launch(void* const* d_in, const int* in_sizes, int n_in,
                              void* d_out, int out_size, void* d_ws, size_t ws_size,
                              hipStream_t stream) {
    (void)in_sizes; (void)n_in; (void)out_size; (void)ws_size;
    const float* pts_img = (const float*)d_in[0];
    const float* img     = (const float*)d_in[1];
    const float* pts     = (const float*)d_in[2];
    const float* fw      = (const float*)d_in[3];
    const float* fbias   = (const float*)d_in[4];
    const float* gamma   = (const float*)d_in[5];
    const float* beta    = (const float*)d_in[6];
    const float* c1w     = (const float*)d_in[7];
    const float* c1b     = (const float*)d_in[8];
    const float* c2w     = (const float*)d_in[9];
    const float* c2b     = (const float*)d_in[10];
    const float* saw     = (const float*)d_in[11];
    const float* sab     = (const float*)d_in[12];
    float* out = (float*)d_out;

    char* ws = (char*)d_ws;
    unsigned short* XT   = (unsigned short*)(ws);              // 67,108,864 B
    unsigned short* Hg   = (unsigned short*)(ws);              // alias: XT dead after gemm1
    unsigned short* imgT = (unsigned short*)(ws + 67108864);   // 20,971,520 B (dead after gather)
    unsigned short* Y    = (unsigned short*)(ws + 67108864);   // 33,554,432 B (overlaps imgT, disjoint lifetime)
    unsigned short* WfB  = (unsigned short*)(ws + 100663296);
    unsigned short* saB  = (unsigned short*)(ws + 100925440);
    unsigned short* ca1B = (unsigned short*)(ws + 100958208);
    unsigned short* ca2B = (unsigned short*)(ws + 100990976);
    float* buckets       = (float*)(ws + 101023744);
    float* ss            = (float*)(ws + 101056512);
    unsigned int* camax  = (unsigned int*)(ws + 101058560);
    float* channel       = (float*)(ws + 101062656);

    k_init<<<1, 256, 0, stream>>>(buckets, camax);
    k_wcvt<<<704, 256, 0, stream>>>(fw, saw, c1w, c2w, WfB, saB, ca1B, ca2B);
    k_imgt<<<dim3(160, 4, 4), 256, 0, stream>>>(img, imgT);
    k_gather<<<4096, 256, 0, stream>>>(pts_img, imgT, XT);
    k_ptst<<<dim3(256, 4, 4), 256, 0, stream>>>(pts, XT);
    k_gemm1<<<dim3(128, 2, 4), 256, 0, stream>>>(WfB, XT, fbias, Y);
    k_bnstats<<<1024, 256, 0, stream>>>(Y, buckets);
    k_bnfin<<<1, 256, 0, stream>>>(buckets, gamma, beta, ss);
    k_bnapply<<<8192, 256, 0, stream>>>(Y, ss);
    k_sa<<<512, 256, 0, stream>>>(Y, saB, sab);
    k_ca1<<<512, 256, 0, stream>>>(Y, ca1B, c1b, Hg);
    k_ca2<<<1024, 256, 0, stream>>>(Hg, ca2B, camax);
    k_chfin<<<4, 256, 0, stream>>>(camax, c2b, channel);
    k_out<<<dim3(256, 4, 4), 256, 0, stream>>>(Y, channel, out);
}

// Round 2
// 295.416 us; speedup vs baseline: 1.1133x; 1.1133x over previous
//
#include <hip/hip_runtime.h>
#include <stdint.h>

// ---------------------------------------------------------------------------
// PointWiseGate, round 2: fused pipeline, 7 kernels.
//   k_wcvt  : weight fp32->bf16 + zero-init buckets/camax
//   k_imgt  : img (B,256,HW) fp32 -> imgT (B,HW,256) bf16
//   k_gather: bilinear gather -> XT[:, 0:256)
//   k_ptst  : pts_feats transpose -> XT[:, 256:512)
//   k_gemm1 : 512->256 conv1x1 via MFMA (global_load_lds staging) + bias
//             + fused BN partial stats (fp32 accs) -> Yraw bf16, buckets
//   k_gate  : BN finalize+apply+ReLU -> sa GEMM+spatial gate -> F (in place)
//             -> ca1 GEMM+ReLU -> ca2 GEMM -> bucketed atomicMax  (all in LDS)
//   k_out   : channel-gate finalize + transpose -> out (B,256,N) fp32
// ---------------------------------------------------------------------------

typedef __attribute__((ext_vector_type(8))) short bf16x8;
typedef __attribute__((ext_vector_type(4))) float f32x4;

#define B_ 4
#define N_ 16384
#define H_ 64
#define W_ 160
#define HW_ (H_ * W_)
#define K_ 512

__device__ __forceinline__ float bf2f(unsigned short u) {
    union { unsigned int i; float f; } c; c.i = ((unsigned int)u) << 16; return c.f;
}
__device__ __forceinline__ unsigned short f2bf(float f) {
    union { float f; unsigned int i; } c; c.f = f;
    unsigned int u = c.i;
    return (unsigned short)((u + 0x7FFFu + ((u >> 16) & 1u)) >> 16);
}
// monotonic float->uint key for atomicMax over signed floats
__device__ __forceinline__ unsigned int fkey(float f) {
    union { float f; unsigned int u; int i; } c; c.f = f;
    return (c.i < 0) ? ~c.u : (c.u | 0x80000000u);
}
__device__ __forceinline__ float funkey(unsigned int k) {
    union { unsigned int u; float f; } c;
    c.u = (k & 0x80000000u) ? (k & 0x7FFFFFFFu) : ~k;
    return c.f;
}

// async global->LDS, 16 B per lane; LDS dest must be wave-uniform base + lane*16
__device__ __forceinline__ void async_copy16(void* lds, const void* g) {
#if defined(__has_builtin) && __has_builtin(__builtin_amdgcn_global_load_lds)
    __builtin_amdgcn_global_load_lds(
        (const __attribute__((address_space(1))) unsigned int*)g,
        (__attribute__((address_space(3))) unsigned int*)lds, 16, 0, 0);
#else
    *(uint4*)lds = *(const uint4*)g;
#endif
}

// ---- weights fp32->bf16 + zero accumulators (block 0 does the init)
__global__ void k_wcvt(const float* __restrict__ fw, const float* __restrict__ saw,
                       const float* __restrict__ c1w, const float* __restrict__ c2w,
                       unsigned short* WfB, unsigned short* saB,
                       unsigned short* ca1B, unsigned short* ca2B,
                       float* buckets, unsigned int* camax) {
    int t = threadIdx.x;
    if (blockIdx.x == 0) {
        for (int i = t; i < 16 * 512; i += 256) buckets[i] = 0.f;
        for (int i = t; i < 8 * 1024; i += 256) camax[i] = 0u;  // key(-inf)=0
    }
    int i = blockIdx.x * 256 + t;
    if (i < 131072) WfB[i] = f2bf(fw[i]);
    else if (i < 147456) saB[i - 131072] = f2bf(saw[i - 131072]);
    else if (i < 163840) ca1B[i - 147456] = f2bf(c1w[i - 147456]);
    else if (i < 180224) ca2B[i - 163840] = f2bf(c2w[i - 163840]);
}

// ---- img (B,256,H*W) fp32 -> imgT (B,H*W,256) bf16   [64x64 LDS tile transpose]
__global__ __launch_bounds__(256) void k_imgt(const float* __restrict__ img,
                                              unsigned short* __restrict__ imgT) {
    __shared__ __align__(16) unsigned short tile[64 * 72];
    int t = threadIdx.x;
    int hw0 = blockIdx.x * 64, c0 = blockIdx.y * 64, b = blockIdx.z;
    const float* src = img + ((size_t)b * 256 + c0) * HW_ + hw0;
    int sub = (t & 15) * 4, grp = t >> 4;
#pragma unroll
    for (int it = 0; it < 4; ++it) {
        int cl = grp + it * 16;
        float4 v = *(const float4*)(src + (size_t)cl * HW_ + sub);
        ushort4 o;
        o.x = f2bf(v.x); o.y = f2bf(v.y); o.z = f2bf(v.z); o.w = f2bf(v.w);
        *(ushort4*)(tile + cl * 72 + sub) = o;
    }
    __syncthreads();
    unsigned short* dst = imgT + ((size_t)b * HW_ + hw0) * 256 + c0;
#pragma unroll
    for (int it = 0; it < 4; ++it) {
        int hwl = grp + it * 16;
        ushort4 o;
        o.x = tile[(sub + 0) * 72 + hwl];
        o.y = tile[(sub + 1) * 72 + hwl];
        o.z = tile[(sub + 2) * 72 + hwl];
        o.w = tile[(sub + 3) * 72 + hwl];
        *(ushort4*)(dst + (size_t)hwl * 256 + sub) = o;
    }
}

// ---- pts_feats (B,256,N) fp32 -> XT[b][n][256+c] bf16
__global__ __launch_bounds__(256) void k_ptst(const float* __restrict__ pts,
                                              unsigned short* __restrict__ XT) {
    __shared__ __align__(16) unsigned short tile[64 * 72];
    int t = threadIdx.x;
    int n0 = blockIdx.x * 64, c0 = blockIdx.y * 64, b = blockIdx.z;
    const float* src = pts + ((size_t)b * 256 + c0) * N_ + n0;
    int sub = (t & 15) * 4, grp = t >> 4;
#pragma unroll
    for (int it = 0; it < 4; ++it) {
        int cl = grp + it * 16;
        float4 v = *(const float4*)(src + (size_t)cl * N_ + sub);
        ushort4 o;
        o.x = f2bf(v.x); o.y = f2bf(v.y); o.z = f2bf(v.z); o.w = f2bf(v.w);
        *(ushort4*)(tile + cl * 72 + sub) = o;
    }
    __syncthreads();
    unsigned short* dst = XT + ((size_t)b * N_ + n0) * K_ + 256 + c0;
#pragma unroll
    for (int it = 0; it < 4; ++it) {
        int nl = grp + it * 16;
        ushort4 o;
        o.x = tile[(sub + 0) * 72 + nl];
        o.y = tile[(sub + 1) * 72 + nl];
        o.z = tile[(sub + 2) * 72 + nl];
        o.w = tile[(sub + 3) * 72 + nl];
        *(ushort4*)(dst + (size_t)nl * K_ + sub) = o;
    }
}

// ---- bilinear grid_sample: imgT gather -> XT[b][n][0..256) bf16
__global__ __launch_bounds__(256) void k_gather(const float* __restrict__ pim,
                                                const unsigned short* __restrict__ imgT,
                                                unsigned short* __restrict__ XT) {
    int t = threadIdx.x;
    int w = t >> 6, lane = t & 63;
    int p0 = blockIdx.x * 16 + w * 4;
    int c = lane * 4;
    for (int pp = 0; pp < 4; ++pp) {
        int p = p0 + pp;
        int b = p >> 14;
        float gx = pim[(size_t)p * 2 + 0];
        float gy = pim[(size_t)p * 2 + 1];
        float x = (gx + 1.0f) * (0.5f * W_) - 0.5f;
        float y = (gy + 1.0f) * (0.5f * H_) - 0.5f;
        float xf = floorf(x), yf = floorf(y);
        float wx1 = x - xf, wx0 = 1.0f - wx1;
        float wy1 = y - yf, wy0 = 1.0f - wy1;
        int x0 = (int)xf, y0 = (int)yf;
        int x1 = x0 + 1, y1 = y0 + 1;
        float vx0 = (x0 >= 0 && x0 < W_) ? 1.f : 0.f;
        float vx1 = (x1 >= 0 && x1 < W_) ? 1.f : 0.f;
        float vy0 = (y0 >= 0 && y0 < H_) ? 1.f : 0.f;
        float vy1 = (y1 >= 0 && y1 < H_) ? 1.f : 0.f;
        int cx0 = min(max(x0, 0), W_ - 1), cx1 = min(max(x1, 0), W_ - 1);
        int cy0 = min(max(y0, 0), H_ - 1), cy1 = min(max(y1, 0), H_ - 1);
        float w00 = wx0 * wy0 * vx0 * vy0;
        float w10 = wx1 * wy0 * vx1 * vy0;
        float w01 = wx0 * wy1 * vx0 * vy1;
        float w11 = wx1 * wy1 * vx1 * vy1;
        const unsigned short* base = imgT + (size_t)b * HW_ * 256;
        ushort4 a00 = *(const ushort4*)(base + ((size_t)cy0 * W_ + cx0) * 256 + c);
        ushort4 a10 = *(const ushort4*)(base + ((size_t)cy0 * W_ + cx1) * 256 + c);
        ushort4 a01 = *(const ushort4*)(base + ((size_t)cy1 * W_ + cx0) * 256 + c);
        ushort4 a11 = *(const ushort4*)(base + ((size_t)cy1 * W_ + cx1) * 256 + c);
        ushort4 o;
        o.x = f2bf(w00 * bf2f(a00.x) + w10 * bf2f(a10.x) + w01 * bf2f(a01.x) + w11 * bf2f(a11.x));
        o.y = f2bf(w00 * bf2f(a00.y) + w10 * bf2f(a10.y) + w01 * bf2f(a01.y) + w11 * bf2f(a11.y));
        o.z = f2bf(w00 * bf2f(a00.z) + w10 * bf2f(a10.z) + w01 * bf2f(a01.z) + w11 * bf2f(a11.z));
        o.w = f2bf(w00 * bf2f(a00.w) + w10 * bf2f(a10.w) + w01 * bf2f(a01.w) + w11 * bf2f(a11.w));
        *(ushort4*)(XT + (size_t)p * K_ + c) = o;
    }
}

// ---- GEMM1 + bias + BN partial stats (from fp32 accumulators)
// Yraw[b][n][m] = Wf[m][:] . XT[b][n][:] + bias[m]; buckets += per-channel sum/sumsq
__global__ __launch_bounds__(256, 2) void k_gemm1(const unsigned short* __restrict__ WfB,
                                                  const unsigned short* __restrict__ XT,
                                                  const float* __restrict__ fb,
                                                  unsigned short* __restrict__ Y,
                                                  float* __restrict__ buckets) {
    __shared__ __align__(16) unsigned short At[128 * 32];
    __shared__ __align__(16) unsigned short Bt[128 * 32];
    __shared__ float biasS[128];
    __shared__ float redS[2][128], redQ[2][128];
    int t = threadIdx.x;
    int n0 = blockIdx.x * 128, m0 = blockIdx.y * 128, b = blockIdx.z;
    if (t < 128) biasS[t] = fb[m0 + t];
    const unsigned short* Xb = XT + (size_t)b * N_ * K_;
    int w = t >> 6, lane = t & 63, quad = lane >> 4, l15 = lane & 15;
    int wm = w >> 1, wn = w & 1;
    // staging: wave w covers row-chunks {2w, 2w+1}; lane -> row chunk*16+(lane>>2), col (lane&3)*8
    int srow = lane >> 2, scol = (lane & 3) * 8;
    const f32x4 fzero = {0.f, 0.f, 0.f, 0.f};
    f32x4 acc[4][4];
#pragma unroll
    for (int i = 0; i < 4; ++i)
#pragma unroll
        for (int j = 0; j < 4; ++j) acc[i][j] = fzero;
    for (int kt = 0; kt < 16; ++kt) {
        int k0 = kt * 32;
        __syncthreads();
#pragma unroll
        for (int cch = 0; cch < 2; ++cch) {
            int chunk = w * 2 + cch;
            int row = chunk * 16 + srow;
            async_copy16(At + chunk * 512 + lane * 8,
                         WfB + (size_t)(m0 + row) * K_ + k0 + scol);
            async_copy16(Bt + chunk * 512 + lane * 8,
                         Xb + (size_t)(n0 + row) * K_ + k0 + scol);
        }
        __syncthreads();
        bf16x8 af[4], bv[4];
#pragma unroll
        for (int i = 0; i < 4; ++i) {
            af[i] = *(const bf16x8*)(At + (wm * 64 + i * 16 + l15) * 32 + quad * 8);
            bv[i] = *(const bf16x8*)(Bt + (wn * 64 + i * 16 + l15) * 32 + quad * 8);
        }
#pragma unroll
        for (int i = 0; i < 4; ++i)
#pragma unroll
            for (int j = 0; j < 4; ++j)
                acc[i][j] = __builtin_amdgcn_mfma_f32_16x16x32_bf16(af[i], bv[j], acc[i][j], 0, 0, 0);
    }
    // epilogue: bias + store bf16 Y + per-channel partial sums over this block's 128 n
    size_t Yb = (size_t)b * N_ * 256;
#pragma unroll
    for (int i = 0; i < 4; ++i) {
        int mloc = wm * 64 + i * 16 + quad * 4;
        float b0 = biasS[mloc + 0], b1 = biasS[mloc + 1];
        float b2 = biasS[mloc + 2], b3 = biasS[mloc + 3];
        float bb[4] = {b0, b1, b2, b3};
#pragma unroll
        for (int j = 0; j < 4; ++j) {
            int n = n0 + wn * 64 + j * 16 + l15;
            ushort4 o;
            o.x = f2bf(acc[i][j][0] + b0);
            o.y = f2bf(acc[i][j][1] + b1);
            o.z = f2bf(acc[i][j][2] + b2);
            o.w = f2bf(acc[i][j][3] + b3);
            *(ushort4*)(Y + Yb + (size_t)n * 256 + m0 + mloc) = o;
        }
#pragma unroll
        for (int r = 0; r < 4; ++r) {
            float s = 0.f, q = 0.f;
#pragma unroll
            for (int j = 0; j < 4; ++j) {
                float y = acc[i][j][r] + bb[r];
                s += y;
                q += y * y;
            }
#pragma unroll
            for (int d = 1; d < 16; d <<= 1) {
                s += __shfl_xor(s, d, 64);
                q += __shfl_xor(q, d, 64);
            }
            if (l15 == 0) {
                redS[wn][mloc + r] = s;
                redQ[wn][mloc + r] = q;
            }
        }
    }
    __syncthreads();
    if (t < 128) {
        float* bk = buckets + (size_t)(blockIdx.x & 15) * 512;
        atomicAdd(bk + m0 + t, redS[0][t] + redS[1][t]);
        atomicAdd(bk + 256 + m0 + t, redQ[0][t] + redQ[1][t]);
    }
}

// ---- fused gate: BN finalize+apply+ReLU -> sa -> spatial gate -> F (write)
//                  -> ca1 -> ca2 -> bucketed atomicMax.  64 points per block.
__global__ __launch_bounds__(256, 1) void k_gate(unsigned short* __restrict__ F,
                                                 const float* __restrict__ buckets,
                                                 const float* __restrict__ gamma,
                                                 const float* __restrict__ beta,
                                                 const unsigned short* __restrict__ saB,
                                                 const float* __restrict__ sab,
                                                 const unsigned short* __restrict__ c1B,
                                                 const float* __restrict__ c1b,
                                                 const unsigned short* __restrict__ c2B,
                                                 unsigned int* __restrict__ camax) {
    __shared__ __align__(16) unsigned short Ft[64 * 264];   // F tile, pts x 256ch (pad)
    __shared__ __align__(16) unsigned short WSb[256 * 72];  // sa/ca1: [64][264]; ca2: [256][72]
    __shared__ __align__(16) unsigned short Ht[64 * 72];    // ca1 output
    __shared__ float scS[256], shS[256];
    __shared__ float biasS[64];
    __shared__ float sp[64];
    int t = threadIdx.x;
    size_t pts0 = (size_t)blockIdx.x * 64;
    int b = (int)(pts0 >> 14);
    int w = t >> 6, lane = t & 63, quad = lane >> 4, l15 = lane & 15;

    // P0: BN finalize (every block recomputes; deterministic) + sa weights + bias
    {
        float s = 0.f, q = 0.f;
#pragma unroll
        for (int bk = 0; bk < 16; ++bk) {
            s += buckets[bk * 512 + t];
            q += buckets[bk * 512 + 256 + t];
        }
        const float inv = 1.0f / (float)(B_ * N_);
        float mean = s * inv;
        float var = q * inv - mean * mean;
        float sc = gamma[t] * rsqrtf(var + 1e-5f);
        scS[t] = sc;
        shS[t] = beta[t] - mean * sc;
    }
    for (int idx = t * 8; idx < 64 * 256; idx += 2048) {
        int r = idx >> 8, c = idx & 255;
        *(uint4*)(WSb + r * 264 + c) = *(const uint4*)(saB + r * 256 + c);
    }
    if (t < 64) biasS[t] = sab[t];
    __syncthreads();

    // P1: stage Yraw -> Ft with BN + ReLU
    for (int idx = t * 8; idx < 64 * 256; idx += 2048) {
        int r = idx >> 8, c = idx & 255;
        uint4 v = *(const uint4*)(F + (pts0 + r) * 256 + c);
        unsigned short* us = (unsigned short*)&v;
#pragma unroll
        for (int e = 0; e < 8; ++e) {
            float f = bf2f(us[e]) * scS[c + e] + shS[c + e];
            us[e] = f2bf(fmaxf(f, 0.f));
        }
        *(uint4*)(Ft + r * 264 + c) = v;
    }
    __syncthreads();

    // P2: sa GEMM (wave w: pts w*16..w*16+15, all 64 j), max over j, sigmoid
    {
        const f32x4 fzero = {0.f, 0.f, 0.f, 0.f};
        f32x4 acc[4] = {fzero, fzero, fzero, fzero};
        for (int kt = 0; kt < 8; ++kt) {
            int k0 = kt * 32;
            bf16x8 af = *(const bf16x8*)(Ft + (w * 16 + l15) * 264 + k0 + quad * 8);
#pragma unroll
            for (int jt = 0; jt < 4; ++jt) {
                bf16x8 bv = *(const bf16x8*)(WSb + (jt * 16 + l15) * 264 + k0 + quad * 8);
                acc[jt] = __builtin_amdgcn_mfma_f32_16x16x32_bf16(af, bv, acc[jt], 0, 0, 0);
            }
        }
        float sb[4];
#pragma unroll
        for (int jt = 0; jt < 4; ++jt) sb[jt] = biasS[jt * 16 + l15];
#pragma unroll
        for (int r = 0; r < 4; ++r) {
            float v = acc[0][r] + sb[0];
            v = fmaxf(v, acc[1][r] + sb[1]);
            v = fmaxf(v, acc[2][r] + sb[2]);
            v = fmaxf(v, acc[3][r] + sb[3]);
#pragma unroll
            for (int d = 1; d < 16; d <<= 1) v = fmaxf(v, __shfl_xor(v, d, 64));
            if (l15 == 0) sp[w * 16 + quad * 4 + r] = 1.0f / (1.0f + __expf(-v));
        }
    }
    __syncthreads();

    // P3: apply spatial gate to Ft, write F to global; load ca1 weights + bias
    for (int idx = t * 8; idx < 64 * 256; idx += 2048) {
        int r = idx >> 8, c = idx & 255;
        float s = sp[r];
        uint4 v = *(uint4*)(Ft + r * 264 + c);
        unsigned short* us = (unsigned short*)&v;
#pragma unroll
        for (int e = 0; e < 8; ++e) us[e] = f2bf(bf2f(us[e]) * s);
        *(uint4*)(Ft + r * 264 + c) = v;
        *(uint4*)(F + (pts0 + r) * 256 + c) = v;
    }
    for (int idx = t * 8; idx < 64 * 256; idx += 2048) {
        int r = idx >> 8, c = idx & 255;
        *(uint4*)(WSb + r * 264 + c) = *(const uint4*)(c1B + r * 256 + c);
    }
    if (t < 64) biasS[t] = c1b[t];
    __syncthreads();

    // P4: ca1 GEMM -> relu -> Ht
    {
        const f32x4 fzero = {0.f, 0.f, 0.f, 0.f};
        f32x4 acc[4] = {fzero, fzero, fzero, fzero};
        for (int kt = 0; kt < 8; ++kt) {
            int k0 = kt * 32;
            bf16x8 af = *(const bf16x8*)(Ft + (w * 16 + l15) * 264 + k0 + quad * 8);
#pragma unroll
            for (int jt = 0; jt < 4; ++jt) {
                bf16x8 bv = *(const bf16x8*)(WSb + (jt * 16 + l15) * 264 + k0 + quad * 8);
                acc[jt] = __builtin_amdgcn_mfma_f32_16x16x32_bf16(af, bv, acc[jt], 0, 0, 0);
            }
        }
#pragma unroll
        for (int jt = 0; jt < 4; ++jt) {
            float bb = biasS[jt * 16 + l15];
#pragma unroll
            for (int r = 0; r < 4; ++r) {
                int pt = w * 16 + quad * 4 + r;
                Ht[pt * 72 + jt * 16 + l15] = f2bf(fmaxf(acc[jt][r] + bb, 0.f));
            }
        }
    }
    __syncthreads();

    // P5: load ca2 weights (256x64 -> stride 72)
    for (int idx = t * 8; idx < 256 * 64; idx += 2048) {
        int r = idx >> 6, c = idx & 63;
        *(uint4*)(WSb + r * 72 + c) = *(const uint4*)(c2B + r * 64 + c);
    }
    __syncthreads();

    // P6: ca2 GEMM (wave w: m2 range w*64.., all 64 pts), max over pts, atomicMax
    {
        const f32x4 fzero = {0.f, 0.f, 0.f, 0.f};
        f32x4 acc[4][4];
#pragma unroll
        for (int i = 0; i < 4; ++i)
#pragma unroll
            for (int mt = 0; mt < 4; ++mt) acc[i][mt] = fzero;
#pragma unroll
        for (int kk = 0; kk < 2; ++kk) {
            bf16x8 af[4], bv[4];
#pragma unroll
            for (int i = 0; i < 4; ++i)
                af[i] = *(const bf16x8*)(Ht + (i * 16 + l15) * 72 + kk * 32 + quad * 8);
#pragma unroll
            for (int mt = 0; mt < 4; ++mt)
                bv[mt] = *(const bf16x8*)(WSb + (w * 64 + mt * 16 + l15) * 72 + kk * 32 + quad * 8);
#pragma unroll
            for (int i = 0; i < 4; ++i)
#pragma unroll
                for (int mt = 0; mt < 4; ++mt)
                    acc[i][mt] = __builtin_amdgcn_mfma_f32_16x16x32_bf16(af[i], bv[mt], acc[i][mt], 0, 0, 0);
        }
        unsigned int* cam = camax + (size_t)(blockIdx.x & 7) * 1024 + b * 256;
#pragma unroll
        for (int mt = 0; mt < 4; ++mt) {
            float v = acc[0][mt][0];
#pragma unroll
            for (int i = 0; i < 4; ++i)
#pragma unroll
                for (int r = 0; r < 4; ++r) v = fmaxf(v, acc[i][mt][r]);
            v = fmaxf(v, __shfl_xor(v, 16, 64));
            v = fmaxf(v, __shfl_xor(v, 32, 64));
            if (quad == 0) atomicMax(cam + w * 64 + mt * 16 + l15, fkey(v));
        }
    }
}

// ---- out[b][m][n] = sigmoid(max+c2b)[b][m] * F[b][n][m]  (transpose, fp32 out)
__global__ __launch_bounds__(256) void k_out(const unsigned short* __restrict__ F,
                                             const unsigned int* __restrict__ camax,
                                             const float* __restrict__ c2b,
                                             float* __restrict__ out) {
    __shared__ __align__(16) unsigned short tile[64 * 72];
    __shared__ float ch[64];
    int t = threadIdx.x;
    int n0 = blockIdx.x * 64, m0 = blockIdx.y * 64, b = blockIdx.z;
    if (t < 64) {
        int m = m0 + t;
        unsigned int k = 0u;
#pragma unroll
        for (int bk = 0; bk < 8; ++bk) k = max(k, camax[bk * 1024 + b * 256 + m]);
        float v = funkey(k) + c2b[m];
        ch[t] = 1.0f / (1.0f + __expf(-v));
    }
    int sub = (t & 15) * 4, grp = t >> 4;
    const unsigned short* src = F + (size_t)b * N_ * 256;
#pragma unroll
    for (int it = 0; it < 4; ++it) {
        int nl = grp + it * 16;
        ushort4 v = *(const ushort4*)(src + (size_t)(n0 + nl) * 256 + m0 + sub);
        *(ushort4*)(tile + nl * 72 + sub) = v;
    }
    __syncthreads();
    float* dst = out + ((size_t)b * 256 + m0) * N_ + n0;
#pragma unroll
    for (int it = 0; it < 4; ++it) {
        int ml = grp + it * 16;
        float g = ch[ml];
        float4 o;
        o.x = bf2f(tile[(sub + 0) * 72 + ml]) * g;
        o.y = bf2f(tile[(sub + 1) * 72 + ml]) * g;
        o.z = bf2f(tile[(sub + 2) * 72 + ml]) * g;
        o.w = bf2f(tile[(sub + 3) * 72 + ml]) * g;
        *(float4*)(dst + (size_t)ml * N_ + sub) = o;
    }
}

extern "C" void kernel_launch(void* const* d_in, const int* in_sizes, int n_in,
                              void* d_out, int out_size, void* d_ws, size_t ws_size,
                              hipStream_t stream) {
    (void)in_sizes; (void)n_in; (void)out_size; (void)ws_size;
    const float* pts_img = (const float*)d_in[0];
    const float* img     = (const float*)d_in[1];
    const float* pts     = (const float*)d_in[2];
    const float* fw      = (const float*)d_in[3];
    const float* fbias   = (const float*)d_in[4];
    const float* gamma   = (const float*)d_in[5];
    const float* beta    = (const float*)d_in[6];
    const float* c1w     = (const float*)d_in[7];
    const float* c1b     = (const float*)d_in[8];
    const float* c2w     = (const float*)d_in[9];
    const float* c2b     = (const float*)d_in[10];
    const float* saw     = (const float*)d_in[11];
    const float* sab     = (const float*)d_in[12];
    float* out = (float*)d_out;

    char* ws = (char*)d_ws;
    unsigned short* XT   = (unsigned short*)(ws);              // 67,108,864 B
    unsigned short* imgT = (unsigned short*)(ws + 67108864);   // 20.97 MB, dead after gather
    unsigned short* Y    = (unsigned short*)(ws + 67108864);   // 33.55 MB (overlaps imgT lifetime-disjoint)
    unsigned short* WfB  = (unsigned short*)(ws + 100663296);  // 262,144 B
    unsigned short* saB  = (unsigned short*)(ws + 100925440);  // 32,768 B
    unsigned short* ca1B = (unsigned short*)(ws + 100958208);  // 32,768 B
    unsigned short* ca2B = (unsigned short*)(ws + 100990976);  // 32,768 B
    float* buckets       = (float*)(ws + 101023744);           // 16*512*4 = 32,768 B
    unsigned int* camax  = (unsigned int*)(ws + 101056512);    // 8*1024*4 = 32,768 B

    k_wcvt<<<704, 256, 0, stream>>>(fw, saw, c1w, c2w, WfB, saB, ca1B, ca2B, buckets, camax);
    k_imgt<<<dim3(160, 4, 4), 256, 0, stream>>>(img, imgT);
    k_gather<<<4096, 256, 0, stream>>>(pts_img, imgT, XT);
    k_ptst<<<dim3(256, 4, 4), 256, 0, stream>>>(pts, XT);
    k_gemm1<<<dim3(128, 2, 4), 256, 0, stream>>>(WfB, XT, fbias, Y, buckets);
    k_gate<<<1024, 256, 0, stream>>>(Y, buckets, gamma, beta, saB, sab, ca1B, c1b, ca2B, camax);
    k_out<<<dim3(256, 4, 4), 256, 0, stream>>>(Y, camax, c2b, out);
}

// Round 3
// 291.782 us; speedup vs baseline: 1.1272x; 1.0125x over previous
//
#include <hip/hip_runtime.h>
#include <stdint.h>

// ---------------------------------------------------------------------------
// PointWiseGate, round 3: 5 kernels.
//   k_imgt  : img (B,256,HW) fp32 -> imgT (B,HW,256) bf16
//   k_xt    : [fused] bilinear gather -> XT[:,0:256) ; pts transpose -> XT[:,256:512)
//             ; weight fp32->bf16 ; bucket/camax init
//   k_gemm1 : 512->256 conv1x1 MFMA (global_load_lds staging) + bias
//             + fused BN partial stats -> Y bf16, buckets
//   k_gate  : BN finalize+apply+ReLU -> sa gate -> F -> ca1 -> ca2 -> atomicMax
//             (weights streamed global->VGPR, no weight LDS; 45.6 KB LDS, 3 blk/CU)
//   k_out   : channel-gate finalize + transpose -> out (B,256,N) fp32
// ---------------------------------------------------------------------------

typedef __attribute__((ext_vector_type(8))) short bf16x8;
typedef __attribute__((ext_vector_type(4))) float f32x4;

#define B_ 4
#define N_ 16384
#define H_ 64
#define W_ 160
#define HW_ (H_ * W_)
#define K_ 512

__device__ __forceinline__ float bf2f(unsigned short u) {
    union { unsigned int i; float f; } c; c.i = ((unsigned int)u) << 16; return c.f;
}
__device__ __forceinline__ unsigned short f2bf(float f) {
    union { float f; unsigned int i; } c; c.f = f;
    unsigned int u = c.i;
    return (unsigned short)((u + 0x7FFFu + ((u >> 16) & 1u)) >> 16);
}
// monotonic float->uint key for atomicMax over signed floats
__device__ __forceinline__ unsigned int fkey(float f) {
    union { float f; unsigned int u; int i; } c; c.f = f;
    return (c.i < 0) ? ~c.u : (c.u | 0x80000000u);
}
__device__ __forceinline__ float funkey(unsigned int k) {
    union { unsigned int u; float f; } c;
    c.u = (k & 0x80000000u) ? (k & 0x7FFFFFFFu) : ~k;
    return c.f;
}

// async global->LDS, 16 B per lane; LDS dest must be wave-uniform base + lane*16
__device__ __forceinline__ void async_copy16(void* lds, const void* g) {
#if defined(__has_builtin) && __has_builtin(__builtin_amdgcn_global_load_lds)
    __builtin_amdgcn_global_load_lds(
        (const __attribute__((address_space(1))) unsigned int*)g,
        (__attribute__((address_space(3))) unsigned int*)lds, 16, 0, 0);
#else
    *(uint4*)lds = *(const uint4*)g;
#endif
}

// ---- img (B,256,H*W) fp32 -> imgT (B,H*W,256) bf16   [64x64 LDS tile transpose]
__global__ __launch_bounds__(256) void k_imgt(const float* __restrict__ img,
                                              unsigned short* __restrict__ imgT) {
    __shared__ __align__(16) unsigned short tile[64 * 72];
    int t = threadIdx.x;
    int hw0 = blockIdx.x * 64, c0 = blockIdx.y * 64, b = blockIdx.z;
    const float* src = img + ((size_t)b * 256 + c0) * HW_ + hw0;
    int sub = (t & 15) * 4, grp = t >> 4;
#pragma unroll
    for (int it = 0; it < 4; ++it) {
        int cl = grp + it * 16;
        float4 v = *(const float4*)(src + (size_t)cl * HW_ + sub);
        ushort4 o;
        o.x = f2bf(v.x); o.y = f2bf(v.y); o.z = f2bf(v.z); o.w = f2bf(v.w);
        *(ushort4*)(tile + cl * 72 + sub) = o;
    }
    __syncthreads();
    unsigned short* dst = imgT + ((size_t)b * HW_ + hw0) * 256 + c0;
#pragma unroll
    for (int it = 0; it < 4; ++it) {
        int hwl = grp + it * 16;
        ushort4 o;
        o.x = tile[(sub + 0) * 72 + hwl];
        o.y = tile[(sub + 1) * 72 + hwl];
        o.z = tile[(sub + 2) * 72 + hwl];
        o.w = tile[(sub + 3) * 72 + hwl];
        *(ushort4*)(dst + (size_t)hwl * 256 + sub) = o;
    }
}

// ---- fused: gather (bx<4096) | pts transpose (bx<8192) | weight cvt + init
__global__ __launch_bounds__(256) void k_xt(const float* __restrict__ pim,
                                            const unsigned short* __restrict__ imgT,
                                            const float* __restrict__ pts,
                                            unsigned short* __restrict__ XT,
                                            const float* __restrict__ fw,
                                            const float* __restrict__ saw,
                                            const float* __restrict__ c1w,
                                            const float* __restrict__ c2w,
                                            unsigned short* WfB, unsigned short* saB,
                                            unsigned short* ca1B, unsigned short* ca2B,
                                            float* buckets, unsigned int* camax) {
    __shared__ __align__(16) unsigned short tile[64 * 72];
    int t = threadIdx.x;
    int bx = blockIdx.x;
    if (bx < 4096) {
        // ---- bilinear gather: 16 points per block, wave = 4 points
        int w = t >> 6, lane = t & 63;
        int p0 = bx * 16 + w * 4;
        int c = lane * 4;
        for (int pp = 0; pp < 4; ++pp) {
            int p = p0 + pp;
            int b = p >> 14;
            float gx = pim[(size_t)p * 2 + 0];
            float gy = pim[(size_t)p * 2 + 1];
            float x = (gx + 1.0f) * (0.5f * W_) - 0.5f;
            float y = (gy + 1.0f) * (0.5f * H_) - 0.5f;
            float xf = floorf(x), yf = floorf(y);
            float wx1 = x - xf, wx0 = 1.0f - wx1;
            float wy1 = y - yf, wy0 = 1.0f - wy1;
            int x0 = (int)xf, y0 = (int)yf;
            int x1 = x0 + 1, y1 = y0 + 1;
            float vx0 = (x0 >= 0 && x0 < W_) ? 1.f : 0.f;
            float vx1 = (x1 >= 0 && x1 < W_) ? 1.f : 0.f;
            float vy0 = (y0 >= 0 && y0 < H_) ? 1.f : 0.f;
            float vy1 = (y1 >= 0 && y1 < H_) ? 1.f : 0.f;
            int cx0 = min(max(x0, 0), W_ - 1), cx1 = min(max(x1, 0), W_ - 1);
            int cy0 = min(max(y0, 0), H_ - 1), cy1 = min(max(y1, 0), H_ - 1);
            float w00 = wx0 * wy0 * vx0 * vy0;
            float w10 = wx1 * wy0 * vx1 * vy0;
            float w01 = wx0 * wy1 * vx0 * vy1;
            float w11 = wx1 * wy1 * vx1 * vy1;
            const unsigned short* base = imgT + (size_t)b * HW_ * 256;
            ushort4 a00 = *(const ushort4*)(base + ((size_t)cy0 * W_ + cx0) * 256 + c);
            ushort4 a10 = *(const ushort4*)(base + ((size_t)cy0 * W_ + cx1) * 256 + c);
            ushort4 a01 = *(const ushort4*)(base + ((size_t)cy1 * W_ + cx0) * 256 + c);
            ushort4 a11 = *(const ushort4*)(base + ((size_t)cy1 * W_ + cx1) * 256 + c);
            ushort4 o;
            o.x = f2bf(w00 * bf2f(a00.x) + w10 * bf2f(a10.x) + w01 * bf2f(a01.x) + w11 * bf2f(a11.x));
            o.y = f2bf(w00 * bf2f(a00.y) + w10 * bf2f(a10.y) + w01 * bf2f(a01.y) + w11 * bf2f(a11.y));
            o.z = f2bf(w00 * bf2f(a00.z) + w10 * bf2f(a10.z) + w01 * bf2f(a01.z) + w11 * bf2f(a11.z));
            o.w = f2bf(w00 * bf2f(a00.w) + w10 * bf2f(a10.w) + w01 * bf2f(a01.w) + w11 * bf2f(a11.w));
            *(ushort4*)(XT + (size_t)p * K_ + c) = o;
        }
    } else if (bx < 8192) {
        // ---- pts_feats (B,256,N) fp32 -> XT[b][n][256+c] bf16
        int j = bx - 4096;
        int n0 = (j & 255) * 64, c0 = ((j >> 8) & 3) * 64, b = j >> 10;
        const float* src = pts + ((size_t)b * 256 + c0) * N_ + n0;
        int sub = (t & 15) * 4, grp = t >> 4;
#pragma unroll
        for (int it = 0; it < 4; ++it) {
            int cl = grp + it * 16;
            float4 v = *(const float4*)(src + (size_t)cl * N_ + sub);
            ushort4 o;
            o.x = f2bf(v.x); o.y = f2bf(v.y); o.z = f2bf(v.z); o.w = f2bf(v.w);
            *(ushort4*)(tile + cl * 72 + sub) = o;
        }
        __syncthreads();
        unsigned short* dst = XT + ((size_t)b * N_ + n0) * K_ + 256 + c0;
#pragma unroll
        for (int it = 0; it < 4; ++it) {
            int nl = grp + it * 16;
            ushort4 o;
            o.x = tile[(sub + 0) * 72 + nl];
            o.y = tile[(sub + 1) * 72 + nl];
            o.z = tile[(sub + 2) * 72 + nl];
            o.w = tile[(sub + 3) * 72 + nl];
            *(ushort4*)(dst + (size_t)nl * K_ + sub) = o;
        }
    } else {
        // ---- weight fp32->bf16 + accumulator init
        int j = bx - 8192;
        if (j == 0) {
            for (int i = t; i < 16 * 512; i += 256) buckets[i] = 0.f;
            for (int i = t; i < 8 * 1024; i += 256) camax[i] = 0u;
        }
        int i = j * 256 + t;
        if (i < 131072) WfB[i] = f2bf(fw[i]);
        else if (i < 147456) saB[i - 131072] = f2bf(saw[i - 131072]);
        else if (i < 163840) ca1B[i - 147456] = f2bf(c1w[i - 147456]);
        else if (i < 180224) ca2B[i - 163840] = f2bf(c2w[i - 163840]);
    }
}

// ---- GEMM1 + bias + BN partial stats (from fp32 accumulators)
__global__ __launch_bounds__(256, 2) void k_gemm1(const unsigned short* __restrict__ WfB,
                                                  const unsigned short* __restrict__ XT,
                                                  const float* __restrict__ fb,
                                                  unsigned short* __restrict__ Y,
                                                  float* __restrict__ buckets) {
    __shared__ __align__(16) unsigned short At[128 * 32];
    __shared__ __align__(16) unsigned short Bt[128 * 32];
    __shared__ float biasS[128];
    __shared__ float redS[2][128], redQ[2][128];
    int t = threadIdx.x;
    int n0 = blockIdx.x * 128, m0 = blockIdx.y * 128, b = blockIdx.z;
    if (t < 128) biasS[t] = fb[m0 + t];
    const unsigned short* Xb = XT + (size_t)b * N_ * K_;
    int w = t >> 6, lane = t & 63, quad = lane >> 4, l15 = lane & 15;
    int wm = w >> 1, wn = w & 1;
    int srow = lane >> 2, scol = (lane & 3) * 8;
    const f32x4 fzero = {0.f, 0.f, 0.f, 0.f};
    f32x4 acc[4][4];
#pragma unroll
    for (int i = 0; i < 4; ++i)
#pragma unroll
        for (int j = 0; j < 4; ++j) acc[i][j] = fzero;
    for (int kt = 0; kt < 16; ++kt) {
        int k0 = kt * 32;
        __syncthreads();
#pragma unroll
        for (int cch = 0; cch < 2; ++cch) {
            int chunk = w * 2 + cch;
            int row = chunk * 16 + srow;
            async_copy16(At + chunk * 512 + lane * 8,
                         WfB + (size_t)(m0 + row) * K_ + k0 + scol);
            async_copy16(Bt + chunk * 512 + lane * 8,
                         Xb + (size_t)(n0 + row) * K_ + k0 + scol);
        }
        __syncthreads();
        bf16x8 af[4], bv[4];
#pragma unroll
        for (int i = 0; i < 4; ++i) {
            af[i] = *(const bf16x8*)(At + (wm * 64 + i * 16 + l15) * 32 + quad * 8);
            bv[i] = *(const bf16x8*)(Bt + (wn * 64 + i * 16 + l15) * 32 + quad * 8);
        }
#pragma unroll
        for (int i = 0; i < 4; ++i)
#pragma unroll
            for (int j = 0; j < 4; ++j)
                acc[i][j] = __builtin_amdgcn_mfma_f32_16x16x32_bf16(af[i], bv[j], acc[i][j], 0, 0, 0);
    }
    size_t Yb = (size_t)b * N_ * 256;
#pragma unroll
    for (int i = 0; i < 4; ++i) {
        int mloc = wm * 64 + i * 16 + quad * 4;
        float b0 = biasS[mloc + 0], b1 = biasS[mloc + 1];
        float b2 = biasS[mloc + 2], b3 = biasS[mloc + 3];
        float bb[4] = {b0, b1, b2, b3};
#pragma unroll
        for (int j = 0; j < 4; ++j) {
            int n = n0 + wn * 64 + j * 16 + l15;
            ushort4 o;
            o.x = f2bf(acc[i][j][0] + b0);
            o.y = f2bf(acc[i][j][1] + b1);
            o.z = f2bf(acc[i][j][2] + b2);
            o.w = f2bf(acc[i][j][3] + b3);
            *(ushort4*)(Y + Yb + (size_t)n * 256 + m0 + mloc) = o;
        }
#pragma unroll
        for (int r = 0; r < 4; ++r) {
            float s = 0.f, q = 0.f;
#pragma unroll
            for (int j = 0; j < 4; ++j) {
                float y = acc[i][j][r] + bb[r];
                s += y;
                q += y * y;
            }
#pragma unroll
            for (int d = 1; d < 16; d <<= 1) {
                s += __shfl_xor(s, d, 64);
                q += __shfl_xor(q, d, 64);
            }
            if (l15 == 0) {
                redS[wn][mloc + r] = s;
                redQ[wn][mloc + r] = q;
            }
        }
    }
    __syncthreads();
    if (t < 128) {
        float* bk = buckets + (size_t)(blockIdx.x & 15) * 512;
        atomicAdd(bk + m0 + t, redS[0][t] + redS[1][t]);
        atomicAdd(bk + 256 + m0 + t, redQ[0][t] + redQ[1][t]);
    }
}

// ---- fused gate: BN finalize+apply+ReLU -> sa -> spatial gate -> F (write)
//                  -> ca1 -> ca2 -> bucketed atomicMax.  64 points per block.
// Weights streamed global->VGPR (L2-resident); LDS 45.6 KB -> 3 blocks/CU.
__global__ __launch_bounds__(256, 3) void k_gate(unsigned short* __restrict__ F,
                                                 const float* __restrict__ buckets,
                                                 const float* __restrict__ gamma,
                                                 const float* __restrict__ beta,
                                                 const unsigned short* __restrict__ saB,
                                                 const float* __restrict__ sab,
                                                 const unsigned short* __restrict__ c1B,
                                                 const float* __restrict__ c1b,
                                                 const unsigned short* __restrict__ c2B,
                                                 unsigned int* __restrict__ camax) {
    __shared__ __align__(16) unsigned short Ft[64 * 264];  // pts x 256ch (pad 8)
    __shared__ __align__(16) unsigned short Ht[64 * 72];   // ca1 output
    __shared__ float scS[256], shS[256];
    __shared__ float sp[64];
    int t = threadIdx.x;
    size_t pts0 = (size_t)blockIdx.x * 64;
    int b = (int)(pts0 >> 14);
    int w = t >> 6, lane = t & 63, quad = lane >> 4, l15 = lane & 15;

    // P0: BN finalize (every block recomputes; deterministic)
    {
        float s = 0.f, q = 0.f;
#pragma unroll
        for (int bk = 0; bk < 16; ++bk) {
            s += buckets[bk * 512 + t];
            q += buckets[bk * 512 + 256 + t];
        }
        const float inv = 1.0f / (float)(B_ * N_);
        float mean = s * inv;
        float var = q * inv - mean * mean;
        float sc = gamma[t] * rsqrtf(var + 1e-5f);
        scS[t] = sc;
        shS[t] = beta[t] - mean * sc;
    }
    __syncthreads();

    // P1: stage Yraw -> Ft with BN + ReLU (sc/sh hoisted: c invariant across iters)
    int cc = (t * 8) & 255;
    float scr[8], shr[8];
#pragma unroll
    for (int e = 0; e < 8; ++e) { scr[e] = scS[cc + e]; shr[e] = shS[cc + e]; }
    for (int idx = t * 8; idx < 64 * 256; idx += 2048) {
        int r = idx >> 8;
        uint4 v = *(const uint4*)(F + (pts0 + r) * 256 + cc);
        unsigned short* us = (unsigned short*)&v;
#pragma unroll
        for (int e = 0; e < 8; ++e) {
            float f = bf2f(us[e]) * scr[e] + shr[e];
            us[e] = f2bf(fmaxf(f, 0.f));
        }
        *(uint4*)(Ft + r * 264 + cc) = v;
    }
    __syncthreads();

    // P2: sa GEMM (wave w: pts w*16.., all 64 j; B-frags streamed from global/L2)
    {
        const f32x4 fzero = {0.f, 0.f, 0.f, 0.f};
        f32x4 acc[4] = {fzero, fzero, fzero, fzero};
        for (int kt = 0; kt < 8; ++kt) {
            int k0 = kt * 32;
            bf16x8 af = *(const bf16x8*)(Ft + (w * 16 + l15) * 264 + k0 + quad * 8);
#pragma unroll
            for (int jt = 0; jt < 4; ++jt) {
                bf16x8 bv = *(const bf16x8*)(saB + (size_t)(jt * 16 + l15) * 256 + k0 + quad * 8);
                acc[jt] = __builtin_amdgcn_mfma_f32_16x16x32_bf16(af, bv, acc[jt], 0, 0, 0);
            }
        }
        float sb[4];
#pragma unroll
        for (int jt = 0; jt < 4; ++jt) sb[jt] = sab[jt * 16 + l15];
#pragma unroll
        for (int r = 0; r < 4; ++r) {
            float v = acc[0][r] + sb[0];
            v = fmaxf(v, acc[1][r] + sb[1]);
            v = fmaxf(v, acc[2][r] + sb[2]);
            v = fmaxf(v, acc[3][r] + sb[3]);
#pragma unroll
            for (int d = 1; d < 16; d <<= 1) v = fmaxf(v, __shfl_xor(v, d, 64));
            if (l15 == 0) sp[w * 16 + quad * 4 + r] = 1.0f / (1.0f + __expf(-v));
        }
    }
    __syncthreads();

    // P3: apply spatial gate to Ft, write F to global
    for (int idx = t * 8; idx < 64 * 256; idx += 2048) {
        int r = idx >> 8;
        float s = sp[r];
        uint4 v = *(uint4*)(Ft + r * 264 + cc);
        unsigned short* us = (unsigned short*)&v;
#pragma unroll
        for (int e = 0; e < 8; ++e) us[e] = f2bf(bf2f(us[e]) * s);
        *(uint4*)(Ft + r * 264 + cc) = v;
        *(uint4*)(F + (pts0 + r) * 256 + cc) = v;
    }
    __syncthreads();

    // P4: ca1 GEMM -> relu -> Ht (B-frags streamed from global/L2)
    {
        const f32x4 fzero = {0.f, 0.f, 0.f, 0.f};
        f32x4 acc[4] = {fzero, fzero, fzero, fzero};
        for (int kt = 0; kt < 8; ++kt) {
            int k0 = kt * 32;
            bf16x8 af = *(const bf16x8*)(Ft + (w * 16 + l15) * 264 + k0 + quad * 8);
#pragma unroll
            for (int jt = 0; jt < 4; ++jt) {
                bf16x8 bv = *(const bf16x8*)(c1B + (size_t)(jt * 16 + l15) * 256 + k0 + quad * 8);
                acc[jt] = __builtin_amdgcn_mfma_f32_16x16x32_bf16(af, bv, acc[jt], 0, 0, 0);
            }
        }
#pragma unroll
        for (int jt = 0; jt < 4; ++jt) {
            float bb = c1b[jt * 16 + l15];
#pragma unroll
            for (int r = 0; r < 4; ++r) {
                int pt = w * 16 + quad * 4 + r;
                Ht[pt * 72 + jt * 16 + l15] = f2bf(fmaxf(acc[jt][r] + bb, 0.f));
            }
        }
    }
    __syncthreads();

    // P5: ca2 GEMM (wave w: m2 = w*64.., all 64 pts), max over pts, atomicMax
    {
        const f32x4 fzero = {0.f, 0.f, 0.f, 0.f};
        f32x4 acc[4][4];
#pragma unroll
        for (int i = 0; i < 4; ++i)
#pragma unroll
            for (int mt = 0; mt < 4; ++mt) acc[i][mt] = fzero;
#pragma unroll
        for (int kk = 0; kk < 2; ++kk) {
            bf16x8 af[4], bv[4];
#pragma unroll
            for (int i = 0; i < 4; ++i)
                af[i] = *(const bf16x8*)(Ht + (i * 16 + l15) * 72 + kk * 32 + quad * 8);
#pragma unroll
            for (int mt = 0; mt < 4; ++mt)
                bv[mt] = *(const bf16x8*)(c2B + (size_t)(w * 64 + mt * 16 + l15) * 64 + kk * 32 + quad * 8);
#pragma unroll
            for (int i = 0; i < 4; ++i)
#pragma unroll
                for (int mt = 0; mt < 4; ++mt)
                    acc[i][mt] = __builtin_amdgcn_mfma_f32_16x16x32_bf16(af[i], bv[mt], acc[i][mt], 0, 0, 0);
        }
        unsigned int* cam = camax + (size_t)(blockIdx.x & 7) * 1024 + b * 256;
#pragma unroll
        for (int mt = 0; mt < 4; ++mt) {
            float v = acc[0][mt][0];
#pragma unroll
            for (int i = 0; i < 4; ++i)
#pragma unroll
                for (int r = 0; r < 4; ++r) v = fmaxf(v, acc[i][mt][r]);
            v = fmaxf(v, __shfl_xor(v, 16, 64));
            v = fmaxf(v, __shfl_xor(v, 32, 64));
            if (quad == 0) atomicMax(cam + w * 64 + mt * 16 + l15, fkey(v));
        }
    }
}

// ---- out[b][m][n] = sigmoid(max+c2b)[b][m] * F[b][n][m]  (transpose, fp32 out)
__global__ __launch_bounds__(256) void k_out(const unsigned short* __restrict__ F,
                                             const unsigned int* __restrict__ camax,
                                             const float* __restrict__ c2b,
                                             float* __restrict__ out) {
    __shared__ __align__(16) unsigned short tile[64 * 72];
    __shared__ float ch[64];
    int t = threadIdx.x;
    int n0 = blockIdx.x * 64, m0 = blockIdx.y * 64, b = blockIdx.z;
    if (t < 64) {
        int m = m0 + t;
        unsigned int k = 0u;
#pragma unroll
        for (int bk = 0; bk < 8; ++bk) k = max(k, camax[bk * 1024 + b * 256 + m]);
        float v = funkey(k) + c2b[m];
        ch[t] = 1.0f / (1.0f + __expf(-v));
    }
    int sub = (t & 15) * 4, grp = t >> 4;
    const unsigned short* src = F + (size_t)b * N_ * 256;
#pragma unroll
    for (int it = 0; it < 4; ++it) {
        int nl = grp + it * 16;
        ushort4 v = *(const ushort4*)(src + (size_t)(n0 + nl) * 256 + m0 + sub);
        *(ushort4*)(tile + nl * 72 + sub) = v;
    }
    __syncthreads();
    float* dst = out + ((size_t)b * 256 + m0) * N_ + n0;
#pragma unroll
    for (int it = 0; it < 4; ++it) {
        int ml = grp + it * 16;
        float g = ch[ml];
        float4 o;
        o.x = bf2f(tile[(sub + 0) * 72 + ml]) * g;
        o.y = bf2f(tile[(sub + 1) * 72 + ml]) * g;
        o.z = bf2f(tile[(sub + 2) * 72 + ml]) * g;
        o.w = bf2f(tile[(sub + 3) * 72 + ml]) * g;
        *(float4*)(dst + (size_t)ml * N_ + sub) = o;
    }
}

extern "C" void kernel_launch(void* const* d_in, const int* in_sizes, int n_in,
                              void* d_out, int out_size, void* d_ws, size_t ws_size,
                              hipStream_t stream) {
    (void)in_sizes; (void)n_in; (void)out_size; (void)ws_size;
    const float* pts_img = (const float*)d_in[0];
    const float* img     = (const float*)d_in[1];
    const float* pts     = (const float*)d_in[2];
    const float* fw      = (const float*)d_in[3];
    const float* fbias   = (const float*)d_in[4];
    const float* gamma   = (const float*)d_in[5];
    const float* beta    = (const float*)d_in[6];
    const float* c1w     = (const float*)d_in[7];
    const float* c1b     = (const float*)d_in[8];
    const float* c2w     = (const float*)d_in[9];
    const float* c2b     = (const float*)d_in[10];
    const float* saw     = (const float*)d_in[11];
    const float* sab     = (const float*)d_in[12];
    float* out = (float*)d_out;

    char* ws = (char*)d_ws;
    unsigned short* XT   = (unsigned short*)(ws);              // 67,108,864 B
    unsigned short* imgT = (unsigned short*)(ws + 67108864);   // 20.97 MB, dead after gather
    unsigned short* Y    = (unsigned short*)(ws + 67108864);   // 33.55 MB (overlaps imgT lifetime-disjoint)
    unsigned short* WfB  = (unsigned short*)(ws + 100663296);  // 262,144 B
    unsigned short* saB  = (unsigned short*)(ws + 100925440);  // 32,768 B
    unsigned short* ca1B = (unsigned short*)(ws + 100958208);  // 32,768 B
    unsigned short* ca2B = (unsigned short*)(ws + 100990976);  // 32,768 B
    float* buckets       = (float*)(ws + 101023744);           // 32,768 B
    unsigned int* camax  = (unsigned int*)(ws + 101056512);    // 32,768 B

    k_imgt<<<dim3(160, 4, 4), 256, 0, stream>>>(img, imgT);
    k_xt<<<8896, 256, 0, stream>>>(pts_img, imgT, pts, XT, fw, saw, c1w, c2w,
                                   WfB, saB, ca1B, ca2B, buckets, camax);
    k_gemm1<<<dim3(128, 2, 4), 256, 0, stream>>>(WfB, XT, fbias, Y, buckets);
    k_gate<<<1024, 256, 0, stream>>>(Y, buckets, gamma, beta, saB, sab, ca1B, c1b, ca2B, camax);
    k_out<<<dim3(256, 4, 4), 256, 0, stream>>>(Y, camax, c2b, out);
}

// Round 4
// 270.731 us; speedup vs baseline: 1.2148x; 1.0778x over previous
//
#include <hip/hip_runtime.h>
#include <stdint.h>

// ---------------------------------------------------------------------------
// PointWiseGate, round 4: 5 kernels, F never materialized.
//   k_imgt  : img (B,256,HW) fp32 -> imgT (B,HW,256) bf16
//   k_xt    : [fused] bilinear gather (XCD-affine batches) -> XT[:,0:256)
//             ; pts transpose -> XT[:,256:512) ; weight cvt ; init
//   k_gemm1 : 512->256 conv1x1 MFMA + bias + fused BN partial stats
//   k_gate  : BN fin+apply+ReLU -> joint sa+ca1 GEMM (weights in VGPRs,
//             shared A-frags) -> sp (to global) -> ca1 epilogue -> ca2 ->
//             bucketed atomicMax. Writes only sp + ss.
//   k_out   : out = sigmoid(max+c2b) * sp * relu(bn(Y))  (transpose, fp32)
// ---------------------------------------------------------------------------

typedef __attribute__((ext_vector_type(8))) short bf16x8;
typedef __attribute__((ext_vector_type(4))) float f32x4;

#define B_ 4
#define N_ 16384
#define H_ 64
#define W_ 160
#define HW_ (H_ * W_)
#define K_ 512

__device__ __forceinline__ float bf2f(unsigned short u) {
    union { unsigned int i; float f; } c; c.i = ((unsigned int)u) << 16; return c.f;
}
__device__ __forceinline__ unsigned short f2bf(float f) {
    union { float f; unsigned int i; } c; c.f = f;
    unsigned int u = c.i;
    return (unsigned short)((u + 0x7FFFu + ((u >> 16) & 1u)) >> 16);
}
// monotonic float->uint key for atomicMax over signed floats
__device__ __forceinline__ unsigned int fkey(float f) {
    union { float f; unsigned int u; int i; } c; c.f = f;
    return (c.i < 0) ? ~c.u : (c.u | 0x80000000u);
}
__device__ __forceinline__ float funkey(unsigned int k) {
    union { unsigned int u; float f; } c;
    c.u = (k & 0x80000000u) ? (k & 0x7FFFFFFFu) : ~k;
    return c.f;
}

// async global->LDS, 16 B per lane; LDS dest must be wave-uniform base + lane*16
__device__ __forceinline__ void async_copy16(void* lds, const void* g) {
#if defined(__has_builtin) && __has_builtin(__builtin_amdgcn_global_load_lds)
    __builtin_amdgcn_global_load_lds(
        (const __attribute__((address_space(1))) unsigned int*)g,
        (__attribute__((address_space(3))) unsigned int*)lds, 16, 0, 0);
#else
    *(uint4*)lds = *(const uint4*)g;
#endif
}

// ---- img (B,256,H*W) fp32 -> imgT (B,H*W,256) bf16   [64x64 LDS tile transpose]
__global__ __launch_bounds__(256) void k_imgt(const float* __restrict__ img,
                                              unsigned short* __restrict__ imgT) {
    __shared__ __align__(16) unsigned short tile[64 * 68];
    int t = threadIdx.x;
    int hw0 = blockIdx.x * 64, c0 = blockIdx.y * 64, b = blockIdx.z;
    const float* src = img + ((size_t)b * 256 + c0) * HW_ + hw0;
    int sub = (t & 15) * 4, grp = t >> 4;
#pragma unroll
    for (int it = 0; it < 4; ++it) {
        int cl = grp + it * 16;
        float4 v = *(const float4*)(src + (size_t)cl * HW_ + sub);
        ushort4 o;
        o.x = f2bf(v.x); o.y = f2bf(v.y); o.z = f2bf(v.z); o.w = f2bf(v.w);
        *(ushort4*)(tile + cl * 68 + sub) = o;
    }
    __syncthreads();
    unsigned short* dst = imgT + ((size_t)b * HW_ + hw0) * 256 + c0;
#pragma unroll
    for (int it = 0; it < 4; ++it) {
        int hwl = grp + it * 16;
        ushort4 o;
        o.x = tile[(sub + 0) * 68 + hwl];
        o.y = tile[(sub + 1) * 68 + hwl];
        o.z = tile[(sub + 2) * 68 + hwl];
        o.w = tile[(sub + 3) * 68 + hwl];
        *(ushort4*)(dst + (size_t)hwl * 256 + sub) = o;
    }
}

// ---- fused: gather (bx<4096, XCD-affine) | pts transpose | weight cvt + init
__global__ __launch_bounds__(256) void k_xt(const float* __restrict__ pim,
                                            const unsigned short* __restrict__ imgT,
                                            const float* __restrict__ pts,
                                            unsigned short* __restrict__ XT,
                                            const float* __restrict__ fw,
                                            const float* __restrict__ saw,
                                            const float* __restrict__ c1w,
                                            const float* __restrict__ c2w,
                                            unsigned short* WfB, unsigned short* saB,
                                            unsigned short* ca1B, unsigned short* ca2B,
                                            float* buckets, unsigned int* camax) {
    __shared__ __align__(16) unsigned short tile[64 * 68];
    int t = threadIdx.x;
    int bx = blockIdx.x;
    if (bx < 4096) {
        // ---- bilinear gather, 16 pts/block, wave = 4 pts.
        // XCD affinity: blocks with bx%8 in {2k,2k+1} serve batch k (round-robin
        // XCD heuristic) so each XCD's L2 sees only one 5.2 MB image.
        int batch = (bx & 7) >> 1;
        int loc = (bx >> 3) * 2 + (bx & 1);           // 0..1023, bijective per batch
        int w = t >> 6, lane = t & 63;
        int p0 = batch * N_ + loc * 16 + w * 4;
        int c = lane * 4;
        const unsigned short* base = imgT + (size_t)batch * HW_ * 256;
        float2 g01[4];
#pragma unroll
        for (int pp = 0; pp < 4; ++pp) g01[pp] = *(const float2*)(pim + (size_t)(p0 + pp) * 2);
        ushort4 a00[4], a10[4], a01[4], a11[4];
        float w00[4], w10[4], w01[4], w11[4];
#pragma unroll
        for (int pp = 0; pp < 4; ++pp) {
            float x = (g01[pp].x + 1.0f) * (0.5f * W_) - 0.5f;
            float y = (g01[pp].y + 1.0f) * (0.5f * H_) - 0.5f;
            float xf = floorf(x), yf = floorf(y);
            float wx1 = x - xf, wx0 = 1.0f - wx1;
            float wy1 = y - yf, wy0 = 1.0f - wy1;
            int x0 = (int)xf, y0 = (int)yf;
            int x1 = x0 + 1, y1 = y0 + 1;
            float vx0 = (x0 >= 0 && x0 < W_) ? 1.f : 0.f;
            float vx1 = (x1 >= 0 && x1 < W_) ? 1.f : 0.f;
            float vy0 = (y0 >= 0 && y0 < H_) ? 1.f : 0.f;
            float vy1 = (y1 >= 0 && y1 < H_) ? 1.f : 0.f;
            int cx0 = min(max(x0, 0), W_ - 1), cx1 = min(max(x1, 0), W_ - 1);
            int cy0 = min(max(y0, 0), H_ - 1), cy1 = min(max(y1, 0), H_ - 1);
            w00[pp] = wx0 * wy0 * vx0 * vy0;
            w10[pp] = wx1 * wy0 * vx1 * vy0;
            w01[pp] = wx0 * wy1 * vx0 * vy1;
            w11[pp] = wx1 * wy1 * vx1 * vy1;
            a00[pp] = *(const ushort4*)(base + ((size_t)cy0 * W_ + cx0) * 256 + c);
            a10[pp] = *(const ushort4*)(base + ((size_t)cy0 * W_ + cx1) * 256 + c);
            a01[pp] = *(const ushort4*)(base + ((size_t)cy1 * W_ + cx0) * 256 + c);
            a11[pp] = *(const ushort4*)(base + ((size_t)cy1 * W_ + cx1) * 256 + c);
        }
#pragma unroll
        for (int pp = 0; pp < 4; ++pp) {
            ushort4 o;
            o.x = f2bf(w00[pp] * bf2f(a00[pp].x) + w10[pp] * bf2f(a10[pp].x) +
                       w01[pp] * bf2f(a01[pp].x) + w11[pp] * bf2f(a11[pp].x));
            o.y = f2bf(w00[pp] * bf2f(a00[pp].y) + w10[pp] * bf2f(a10[pp].y) +
                       w01[pp] * bf2f(a01[pp].y) + w11[pp] * bf2f(a11[pp].y));
            o.z = f2bf(w00[pp] * bf2f(a00[pp].z) + w10[pp] * bf2f(a10[pp].z) +
                       w01[pp] * bf2f(a01[pp].z) + w11[pp] * bf2f(a11[pp].z));
            o.w = f2bf(w00[pp] * bf2f(a00[pp].w) + w10[pp] * bf2f(a10[pp].w) +
                       w01[pp] * bf2f(a01[pp].w) + w11[pp] * bf2f(a11[pp].w));
            *(ushort4*)(XT + (size_t)(p0 + pp) * K_ + c) = o;
        }
    } else if (bx < 8192) {
        // ---- pts_feats (B,256,N) fp32 -> XT[b][n][256+c] bf16
        int j = bx - 4096;
        int n0 = (j & 255) * 64, c0 = ((j >> 8) & 3) * 64, b = j >> 10;
        const float* src = pts + ((size_t)b * 256 + c0) * N_ + n0;
        int sub = (t & 15) * 4, grp = t >> 4;
#pragma unroll
        for (int it = 0; it < 4; ++it) {
            int cl = grp + it * 16;
            float4 v = *(const float4*)(src + (size_t)cl * N_ + sub);
            ushort4 o;
            o.x = f2bf(v.x); o.y = f2bf(v.y); o.z = f2bf(v.z); o.w = f2bf(v.w);
            *(ushort4*)(tile + cl * 68 + sub) = o;
        }
        __syncthreads();
        unsigned short* dst = XT + ((size_t)b * N_ + n0) * K_ + 256 + c0;
#pragma unroll
        for (int it = 0; it < 4; ++it) {
            int nl = grp + it * 16;
            ushort4 o;
            o.x = tile[(sub + 0) * 68 + nl];
            o.y = tile[(sub + 1) * 68 + nl];
            o.z = tile[(sub + 2) * 68 + nl];
            o.w = tile[(sub + 3) * 68 + nl];
            *(ushort4*)(dst + (size_t)nl * K_ + sub) = o;
        }
    } else {
        // ---- weight fp32->bf16 + accumulator init
        int j = bx - 8192;
        if (j == 0) {
            for (int i = t; i < 16 * 512; i += 256) buckets[i] = 0.f;
            for (int i = t; i < 8 * 1024; i += 256) camax[i] = 0u;
        }
        int i = j * 256 + t;
        if (i < 131072) WfB[i] = f2bf(fw[i]);
        else if (i < 147456) saB[i - 131072] = f2bf(saw[i - 131072]);
        else if (i < 163840) ca1B[i - 147456] = f2bf(c1w[i - 147456]);
        else if (i < 180224) ca2B[i - 163840] = f2bf(c2w[i - 163840]);
    }
}

// ---- GEMM1 + bias + BN partial stats (fp32 accumulators). m fastest for L2 pairing.
__global__ __launch_bounds__(256, 2) void k_gemm1(const unsigned short* __restrict__ WfB,
                                                  const unsigned short* __restrict__ XT,
                                                  const float* __restrict__ fb,
                                                  unsigned short* __restrict__ Y,
                                                  float* __restrict__ buckets) {
    __shared__ __align__(16) unsigned short At[128 * 32];
    __shared__ __align__(16) unsigned short Bt[128 * 32];
    __shared__ float biasS[128];
    __shared__ float redS[2][128], redQ[2][128];
    int t = threadIdx.x;
    int m0 = blockIdx.x * 128, n0 = blockIdx.y * 128, b = blockIdx.z;
    if (t < 128) biasS[t] = fb[m0 + t];
    const unsigned short* Xb = XT + (size_t)b * N_ * K_;
    int w = t >> 6, lane = t & 63, quad = lane >> 4, l15 = lane & 15;
    int wm = w >> 1, wn = w & 1;
    int srow = lane >> 2, scol = (lane & 3) * 8;
    const f32x4 fzero = {0.f, 0.f, 0.f, 0.f};
    f32x4 acc[4][4];
#pragma unroll
    for (int i = 0; i < 4; ++i)
#pragma unroll
        for (int j = 0; j < 4; ++j) acc[i][j] = fzero;
    for (int kt = 0; kt < 16; ++kt) {
        int k0 = kt * 32;
        __syncthreads();
#pragma unroll
        for (int cch = 0; cch < 2; ++cch) {
            int chunk = w * 2 + cch;
            int row = chunk * 16 + srow;
            async_copy16(At + chunk * 512 + lane * 8,
                         WfB + (size_t)(m0 + row) * K_ + k0 + scol);
            async_copy16(Bt + chunk * 512 + lane * 8,
                         Xb + (size_t)(n0 + row) * K_ + k0 + scol);
        }
        __syncthreads();
        bf16x8 af[4], bv[4];
#pragma unroll
        for (int i = 0; i < 4; ++i) {
            af[i] = *(const bf16x8*)(At + (wm * 64 + i * 16 + l15) * 32 + quad * 8);
            bv[i] = *(const bf16x8*)(Bt + (wn * 64 + i * 16 + l15) * 32 + quad * 8);
        }
#pragma unroll
        for (int i = 0; i < 4; ++i)
#pragma unroll
            for (int j = 0; j < 4; ++j)
                acc[i][j] = __builtin_amdgcn_mfma_f32_16x16x32_bf16(af[i], bv[j], acc[i][j], 0, 0, 0);
    }
    size_t Yb = (size_t)b * N_ * 256;
#pragma unroll
    for (int i = 0; i < 4; ++i) {
        int mloc = wm * 64 + i * 16 + quad * 4;
        float b0 = biasS[mloc + 0], b1 = biasS[mloc + 1];
        float b2 = biasS[mloc + 2], b3 = biasS[mloc + 3];
        float bb[4] = {b0, b1, b2, b3};
#pragma unroll
        for (int j = 0; j < 4; ++j) {
            int n = n0 + wn * 64 + j * 16 + l15;
            ushort4 o;
            o.x = f2bf(acc[i][j][0] + b0);
            o.y = f2bf(acc[i][j][1] + b1);
            o.z = f2bf(acc[i][j][2] + b2);
            o.w = f2bf(acc[i][j][3] + b3);
            *(ushort4*)(Y + Yb + (size_t)n * 256 + m0 + mloc) = o;
        }
#pragma unroll
        for (int r = 0; r < 4; ++r) {
            float s = 0.f, q = 0.f;
#pragma unroll
            for (int j = 0; j < 4; ++j) {
                float y = acc[i][j][r] + bb[r];
                s += y;
                q += y * y;
            }
#pragma unroll
            for (int d = 1; d < 16; d <<= 1) {
                s += __shfl_xor(s, d, 64);
                q += __shfl_xor(q, d, 64);
            }
            if (l15 == 0) {
                redS[wn][mloc + r] = s;
                redQ[wn][mloc + r] = q;
            }
        }
    }
    __syncthreads();
    if (t < 128) {
        float* bk = buckets + (size_t)(blockIdx.y & 15) * 512;
        atomicAdd(bk + m0 + t, redS[0][t] + redS[1][t]);
        atomicAdd(bk + 256 + m0 + t, redQ[0][t] + redQ[1][t]);
    }
}

// ---- fused gate: BN fin+apply+ReLU -> joint sa+ca1 (weights in VGPRs, shared
// A-frags) -> sp -> ca1 epilogue (sp-scaled accs) -> ca2 -> atomicMax.
// 64 pts/block; writes only sp (+ss from block 0). Y read-only.
__global__ __launch_bounds__(256, 2) void k_gate(const unsigned short* __restrict__ Y,
                                                 const float* __restrict__ buckets,
                                                 const float* __restrict__ gamma,
                                                 const float* __restrict__ beta,
                                                 const unsigned short* __restrict__ saB,
                                                 const float* __restrict__ sab,
                                                 const unsigned short* __restrict__ c1B,
                                                 const float* __restrict__ c1b,
                                                 const unsigned short* __restrict__ c2B,
                                                 unsigned int* __restrict__ camax,
                                                 float* __restrict__ sp_g,
                                                 float* __restrict__ ss_out) {
    __shared__ __align__(16) unsigned short Ft[64 * 264];  // relu(bn(Y)), UNGATED
    __shared__ __align__(16) unsigned short Ht[64 * 72];   // ca1 output
    __shared__ float scS[256], shS[256];
    __shared__ float saPart[4][64];
    __shared__ float spL[64];
    int t = threadIdx.x;
    size_t pts0 = (size_t)blockIdx.x * 64;
    int b = (int)(pts0 >> 14);
    int w = t >> 6, lane = t & 63, quad = lane >> 4, l15 = lane & 15;
    int jrow = w * 16 + l15;  // wave w owns j/h channels [w*16, w*16+16)

    // early: preload sa+ca1 weight fragments into VGPRs (overlaps P0/P1)
    bf16x8 bvs[8], bvc[8];
#pragma unroll
    for (int kt = 0; kt < 8; ++kt) {
        bvs[kt] = *(const bf16x8*)(saB + (size_t)jrow * 256 + kt * 32 + quad * 8);
        bvc[kt] = *(const bf16x8*)(c1B + (size_t)jrow * 256 + kt * 32 + quad * 8);
    }
    float sbias = sab[jrow];
    float cbias = c1b[jrow];

    // P0: BN finalize (per-block recompute; deterministic)
    {
        float s = 0.f, q = 0.f;
#pragma unroll
        for (int bk = 0; bk < 16; ++bk) {
            s += buckets[bk * 512 + t];
            q += buckets[bk * 512 + 256 + t];
        }
        const float inv = 1.0f / (float)(B_ * N_);
        float mean = s * inv;
        float var = q * inv - mean * mean;
        float sc = gamma[t] * rsqrtf(var + 1e-5f);
        float sh = beta[t] - mean * sc;
        scS[t] = sc;
        shS[t] = sh;
        if (blockIdx.x == 0) { ss_out[t] = sc; ss_out[256 + t] = sh; }
    }
    __syncthreads();

    // P1: Y -> Ft with BN + ReLU
    int cc = (t * 8) & 255;
    float scr[8], shr[8];
#pragma unroll
    for (int e = 0; e < 8; ++e) { scr[e] = scS[cc + e]; shr[e] = shS[cc + e]; }
    for (int idx = t * 8; idx < 64 * 256; idx += 2048) {
        int r = idx >> 8;
        uint4 v = *(const uint4*)(Y + (pts0 + r) * 256 + cc);
        unsigned short* us = (unsigned short*)&v;
#pragma unroll
        for (int e = 0; e < 8; ++e) {
            float f = bf2f(us[e]) * scr[e] + shr[e];
            us[e] = f2bf(fmaxf(f, 0.f));
        }
        *(uint4*)(Ft + r * 264 + cc) = v;
    }
    __syncthreads();

    // P2: joint sa+ca1 GEMM on UNGATED Ft (shared A-frags, weights in regs)
    const f32x4 fzero = {0.f, 0.f, 0.f, 0.f};
    f32x4 accS[4], accC[4];
#pragma unroll
    for (int i = 0; i < 4; ++i) { accS[i] = fzero; accC[i] = fzero; }
#pragma unroll
    for (int kt = 0; kt < 8; ++kt) {
        bf16x8 af[4];
#pragma unroll
        for (int i = 0; i < 4; ++i)
            af[i] = *(const bf16x8*)(Ft + (i * 16 + l15) * 264 + kt * 32 + quad * 8);
#pragma unroll
        for (int i = 0; i < 4; ++i) {
            accS[i] = __builtin_amdgcn_mfma_f32_16x16x32_bf16(af[i], bvs[kt], accS[i], 0, 0, 0);
            accC[i] = __builtin_amdgcn_mfma_f32_16x16x32_bf16(af[i], bvc[kt], accC[i], 0, 0, 0);
        }
    }
    // sa partial: per-pt max over this wave's 16 j (bias added pre-max)
#pragma unroll
    for (int i = 0; i < 4; ++i) {
#pragma unroll
        for (int r = 0; r < 4; ++r) {
            float v = accS[i][r] + sbias;
#pragma unroll
            for (int d = 1; d < 16; d <<= 1) v = fmaxf(v, __shfl_xor(v, d, 64));
            if (l15 == 0) saPart[w][i * 16 + quad * 4 + r] = v;
        }
    }
    __syncthreads();
    if (t < 64) {
        float m4 = fmaxf(fmaxf(saPart[0][t], saPart[1][t]),
                         fmaxf(saPart[2][t], saPart[3][t]));
        float sv = 1.0f / (1.0f + __expf(-m4));
        spL[t] = sv;
        sp_g[pts0 + t] = sv;
    }
    __syncthreads();

    // P3: ca1 epilogue — scale rows by sp (linearity), +bias, relu -> Ht
#pragma unroll
    for (int i = 0; i < 4; ++i) {
#pragma unroll
        for (int r = 0; r < 4; ++r) {
            int pt = i * 16 + quad * 4 + r;
            float hv = fmaxf(accC[i][r] * spL[pt] + cbias, 0.f);
            Ht[pt * 72 + jrow] = f2bf(hv);
        }
    }
    __syncthreads();

    // P4: ca2 (wave w owns m2 in [w*64, w*64+64)), max over pts, atomicMax
    {
        bf16x8 b2a[4], b2b[4];
#pragma unroll
        for (int mt = 0; mt < 4; ++mt) {
            b2a[mt] = *(const bf16x8*)(c2B + (size_t)(w * 64 + mt * 16 + l15) * 64 + quad * 8);
            b2b[mt] = *(const bf16x8*)(c2B + (size_t)(w * 64 + mt * 16 + l15) * 64 + 32 + quad * 8);
        }
        float vmax[4] = {-3e38f, -3e38f, -3e38f, -3e38f};
#pragma unroll
        for (int i = 0; i < 4; ++i) {
            bf16x8 a0 = *(const bf16x8*)(Ht + (i * 16 + l15) * 72 + quad * 8);
            bf16x8 a1 = *(const bf16x8*)(Ht + (i * 16 + l15) * 72 + 32 + quad * 8);
#pragma unroll
            for (int mt = 0; mt < 4; ++mt) {
                f32x4 acc = __builtin_amdgcn_mfma_f32_16x16x32_bf16(a0, b2a[mt], fzero, 0, 0, 0);
                acc = __builtin_amdgcn_mfma_f32_16x16x32_bf16(a1, b2b[mt], acc, 0, 0, 0);
#pragma unroll
                for (int r = 0; r < 4; ++r) vmax[mt] = fmaxf(vmax[mt], acc[r]);
            }
        }
        unsigned int* cam = camax + (size_t)(blockIdx.x & 7) * 1024 + b * 256;
#pragma unroll
        for (int mt = 0; mt < 4; ++mt) {
            float v = vmax[mt];
            v = fmaxf(v, __shfl_xor(v, 16, 64));
            v = fmaxf(v, __shfl_xor(v, 32, 64));
            if (quad == 0) atomicMax(cam + w * 64 + mt * 16 + l15, fkey(v));
        }
    }
}

// ---- out[b][m][n] = sigmoid(max+c2b)[b][m] * sp[b][n] * relu(bn(Y[b][n][m]))
__global__ __launch_bounds__(256) void k_out(const unsigned short* __restrict__ Y,
                                             const unsigned int* __restrict__ camax,
                                             const float* __restrict__ c2b,
                                             const float* __restrict__ ss,
                                             const float* __restrict__ sp_g,
                                             float* __restrict__ out) {
    __shared__ __align__(16) unsigned short tile[64 * 68];
    __shared__ float ch[64], scT[64], shT[64], spT[64];
    int t = threadIdx.x;
    int n0 = blockIdx.x * 64, m0 = blockIdx.y * 64, b = blockIdx.z;
    if (t < 64) {
        int m = m0 + t;
        unsigned int k = 0u;
#pragma unroll
        for (int bk = 0; bk < 8; ++bk) k = max(k, camax[bk * 1024 + b * 256 + m]);
        ch[t] = 1.0f / (1.0f + __expf(-(funkey(k) + c2b[m])));
        scT[t] = ss[m];
        shT[t] = ss[256 + m];
        spT[t] = sp_g[(size_t)b * N_ + n0 + t];
    }
    int sub = (t & 15) * 4, grp = t >> 4;
    const unsigned short* src = Y + ((size_t)b * N_ + n0) * 256 + m0;
#pragma unroll
    for (int it = 0; it < 4; ++it) {
        int nl = grp + it * 16;
        ushort4 v = *(const ushort4*)(src + (size_t)nl * 256 + sub);
        *(ushort4*)(tile + nl * 68 + sub) = v;
    }
    __syncthreads();
    float* dst = out + ((size_t)b * 256 + m0) * N_ + n0;
#pragma unroll
    for (int it = 0; it < 4; ++it) {
        int ml = grp + it * 16;
        float g = ch[ml], scv = scT[ml], shv = shT[ml];
        float4 o;
        o.x = fmaxf(bf2f(tile[(sub + 0) * 68 + ml]) * scv + shv, 0.f) * spT[sub + 0] * g;
        o.y = fmaxf(bf2f(tile[(sub + 1) * 68 + ml]) * scv + shv, 0.f) * spT[sub + 1] * g;
        o.z = fmaxf(bf2f(tile[(sub + 2) * 68 + ml]) * scv + shv, 0.f) * spT[sub + 2] * g;
        o.w = fmaxf(bf2f(tile[(sub + 3) * 68 + ml]) * scv + shv, 0.f) * spT[sub + 3] * g;
        *(float4*)(dst + (size_t)ml * N_ + sub) = o;
    }
}

extern "C" void kernel_launch(void* const* d_in, const int* in_sizes, int n_in,
                              void* d_out, int out_size, void* d_ws, size_t ws_size,
                              hipStream_t stream) {
    (void)in_sizes; (void)n_in; (void)out_size; (void)ws_size;
    const float* pts_img = (const float*)d_in[0];
    const float* img     = (const float*)d_in[1];
    const float* pts     = (const float*)d_in[2];
    const float* fw      = (const float*)d_in[3];
    const float* fbias   = (const float*)d_in[4];
    const float* gamma   = (const float*)d_in[5];
    const float* beta    = (const float*)d_in[6];
    const float* c1w     = (const float*)d_in[7];
    const float* c1b     = (const float*)d_in[8];
    const float* c2w     = (const float*)d_in[9];
    const float* c2b     = (const float*)d_in[10];
    const float* saw     = (const float*)d_in[11];
    const float* sab     = (const float*)d_in[12];
    float* out = (float*)d_out;

    char* ws = (char*)d_ws;
    unsigned short* XT   = (unsigned short*)(ws);              // 67,108,864 B
    unsigned short* imgT = (unsigned short*)(ws + 67108864);   // 20.97 MB, dead after k_xt
    unsigned short* Y    = (unsigned short*)(ws + 67108864);   // 33.55 MB (overlaps imgT)
    unsigned short* WfB  = (unsigned short*)(ws + 100663296);
    unsigned short* saB  = (unsigned short*)(ws + 100925440);
    unsigned short* ca1B = (unsigned short*)(ws + 100958208);
    unsigned short* ca2B = (unsigned short*)(ws + 100990976);
    float* buckets       = (float*)(ws + 101023744);
    unsigned int* camax  = (unsigned int*)(ws + 101056512);
    float* sp_g          = (float*)(ws + 101089280);           // 262,144 B
    float* ss            = (float*)(ws + 101351424);           // 2,048 B

    k_imgt<<<dim3(160, 4, 4), 256, 0, stream>>>(img, imgT);
    k_xt<<<8896, 256, 0, stream>>>(pts_img, imgT, pts, XT, fw, saw, c1w, c2w,
                                   WfB, saB, ca1B, ca2B, buckets, camax);
    k_gemm1<<<dim3(2, 128, 4), 256, 0, stream>>>(WfB, XT, fbias, Y, buckets);
    k_gate<<<1024, 256, 0, stream>>>(Y, buckets, gamma, beta, saB, sab, ca1B, c1b,
                                     ca2B, camax, sp_g, ss);
    k_out<<<dim3(256, 4, 4), 256, 0, stream>>>(Y, camax, c2b, ss, sp_g, out);
}

// Round 5
// 245.165 us; speedup vs baseline: 1.3415x; 1.1043x over previous
//
#include <hip/hip_runtime.h>
#include <stdint.h>

// ---------------------------------------------------------------------------
// PointWiseGate, round 5: 4 kernels, XT eliminated.
//   k_imgt  : img -> imgT (B,HW,256) bf16  [+ weight cvt + init, folded]
//   k_gemm1f: fused GEMM1 — B-operand staged on the fly:
//               K[0,256)  = bilinear gather from imgT (offsets precomputed/block)
//               K[256,512)= fp32 pts load + LDS transpose
//             full M=256 per block (acc 4x8), LDS epilogue -> coalesced Y stores,
//             + bias + BN partial stats.
//   k_gate  : BN fin+apply+ReLU -> joint sa+ca1 -> sp -> ca2 -> atomicMax
//   k_out   : out = sigmoid(max+c2b) * sp * relu(bn(Y))
// ---------------------------------------------------------------------------

typedef __attribute__((ext_vector_type(8))) short bf16x8;
typedef __attribute__((ext_vector_type(4))) float f32x4;

#define B_ 4
#define N_ 16384
#define H_ 64
#define W_ 160
#define HW_ (H_ * W_)
#define K_ 512

__device__ __forceinline__ float bf2f(unsigned short u) {
    union { unsigned int i; float f; } c; c.i = ((unsigned int)u) << 16; return c.f;
}
__device__ __forceinline__ unsigned short f2bf(float f) {
    union { float f; unsigned int i; } c; c.f = f;
    unsigned int u = c.i;
    return (unsigned short)((u + 0x7FFFu + ((u >> 16) & 1u)) >> 16);
}
__device__ __forceinline__ unsigned int fkey(float f) {
    union { float f; unsigned int u; int i; } c; c.f = f;
    return (c.i < 0) ? ~c.u : (c.u | 0x80000000u);
}
__device__ __forceinline__ float funkey(unsigned int k) {
    union { unsigned int u; float f; } c;
    c.u = (k & 0x80000000u) ? (k & 0x7FFFFFFFu) : ~k;
    return c.f;
}

__device__ __forceinline__ void async_copy16(void* lds, const void* g) {
#if defined(__has_builtin) && __has_builtin(__builtin_amdgcn_global_load_lds)
    __builtin_amdgcn_global_load_lds(
        (const __attribute__((address_space(1))) unsigned int*)g,
        (__attribute__((address_space(3))) unsigned int*)lds, 16, 0, 0);
#else
    *(uint4*)lds = *(const uint4*)g;
#endif
}

// ---- img transpose + weight cvt + init (1D grid: 2560 transpose + 704 weights)
__global__ __launch_bounds__(256) void k_imgt(const float* __restrict__ img,
                                              unsigned short* __restrict__ imgT,
                                              const float* __restrict__ fw,
                                              const float* __restrict__ saw,
                                              const float* __restrict__ c1w,
                                              const float* __restrict__ c2w,
                                              unsigned short* WfB, unsigned short* saB,
                                              unsigned short* ca1B, unsigned short* ca2B,
                                              float* buckets, unsigned int* camax) {
    int t = threadIdx.x;
    int bx = blockIdx.x;
    if (bx < 2560) {
        __shared__ __align__(16) unsigned short tile[64 * 68];
        int hw0 = (bx % 160) * 64, c0 = ((bx / 160) & 3) * 64, b = bx / 640;
        const float* src = img + ((size_t)b * 256 + c0) * HW_ + hw0;
        int sub = (t & 15) * 4, grp = t >> 4;
#pragma unroll
        for (int it = 0; it < 4; ++it) {
            int cl = grp + it * 16;
            float4 v = *(const float4*)(src + (size_t)cl * HW_ + sub);
            ushort4 o;
            o.x = f2bf(v.x); o.y = f2bf(v.y); o.z = f2bf(v.z); o.w = f2bf(v.w);
            *(ushort4*)(tile + cl * 68 + sub) = o;
        }
        __syncthreads();
        unsigned short* dst = imgT + ((size_t)b * HW_ + hw0) * 256 + c0;
#pragma unroll
        for (int it = 0; it < 4; ++it) {
            int hwl = grp + it * 16;
            ushort4 o;
            o.x = tile[(sub + 0) * 68 + hwl];
            o.y = tile[(sub + 1) * 68 + hwl];
            o.z = tile[(sub + 2) * 68 + hwl];
            o.w = tile[(sub + 3) * 68 + hwl];
            *(ushort4*)(dst + (size_t)hwl * 256 + sub) = o;
        }
    } else {
        int j = bx - 2560;
        if (j == 0) {
            for (int i = t; i < 16 * 512; i += 256) buckets[i] = 0.f;
            for (int i = t; i < 8 * 1024; i += 256) camax[i] = 0u;
        }
        int i = j * 256 + t;
        if (i < 131072) WfB[i] = f2bf(fw[i]);
        else if (i < 147456) saB[i - 131072] = f2bf(saw[i - 131072]);
        else if (i < 163840) ca1B[i - 147456] = f2bf(c1w[i - 147456]);
        else if (i < 180224) ca2B[i - 163840] = f2bf(c2w[i - 163840]);
    }
}

// ---- fused GEMM1: Y[b][n][m] = Wf[m][:].X[b][n][:] + bias; X staged on the fly.
// Block: full M=256 x 128 n. Waves: w owns m [w*64, w*64+64). acc[4][8].
__global__ __launch_bounds__(256, 2) void k_gemm1f(const unsigned short* __restrict__ WfB,
                                                   const float* __restrict__ pim,
                                                   const unsigned short* __restrict__ imgT,
                                                   const float* __restrict__ pts,
                                                   const float* __restrict__ fb,
                                                   unsigned short* __restrict__ Y,
                                                   float* __restrict__ buckets) {
    __shared__ __align__(16) char smem[37888];
    unsigned short* At = (unsigned short*)smem;                 // [256][32] 16384 B
    unsigned short* Bt = (unsigned short*)(smem + 16384);       // [128][40] 10240 B
    uint4*  offs4 = (uint4*)(smem + 26624);                     // [128] 2048 B
    float4* wts4  = (float4*)(smem + 28672);                    // [128] 2048 B
    unsigned short* tile = (unsigned short*)smem;               // epi: [128][136] 34816 B
    float* biasS = (float*)(smem + 34816);                      // 1024 B
    float* redS  = (float*)(smem + 35840);                      // 1024 B
    float* redQ  = (float*)(smem + 36864);                      // 1024 B

    int t = threadIdx.x;
    int n0 = blockIdx.x * 128, bb = blockIdx.y;
    int w = t >> 6, lane = t & 63, quad = lane >> 4, l15 = lane & 15;
    const unsigned short* imb = imgT + (size_t)bb * HW_ * 256;

    // precompute bilinear corners for this block's 128 points
    if (t < 128) {
        float2 g2 = *(const float2*)(pim + (size_t)((size_t)bb * N_ + n0 + t) * 2);
        float x = (g2.x + 1.0f) * (0.5f * W_) - 0.5f;
        float y = (g2.y + 1.0f) * (0.5f * H_) - 0.5f;
        float xf = floorf(x), yf = floorf(y);
        float wx1 = x - xf, wx0 = 1.0f - wx1;
        float wy1 = y - yf, wy0 = 1.0f - wy1;
        int x0 = (int)xf, y0 = (int)yf;
        int x1 = x0 + 1, y1 = y0 + 1;
        float vx0 = (x0 >= 0 && x0 < W_) ? 1.f : 0.f;
        float vx1 = (x1 >= 0 && x1 < W_) ? 1.f : 0.f;
        float vy0 = (y0 >= 0 && y0 < H_) ? 1.f : 0.f;
        float vy1 = (y1 >= 0 && y1 < H_) ? 1.f : 0.f;
        int cx0 = min(max(x0, 0), W_ - 1), cx1 = min(max(x1, 0), W_ - 1);
        int cy0 = min(max(y0, 0), H_ - 1), cy1 = min(max(y1, 0), H_ - 1);
        uint4 o4;
        o4.x = (unsigned)(cy0 * W_ + cx0);
        o4.y = (unsigned)(cy0 * W_ + cx1);
        o4.z = (unsigned)(cy1 * W_ + cx0);
        o4.w = (unsigned)(cy1 * W_ + cx1);
        offs4[t] = o4;
        float4 w4;
        w4.x = wx0 * wy0 * vx0 * vy0;
        w4.y = wx1 * wy0 * vx1 * vy0;
        w4.z = wx0 * wy1 * vx0 * vy1;
        w4.w = wx1 * wy1 * vx1 * vy1;
        wts4[t] = w4;
    }

    const f32x4 fzero = {0.f, 0.f, 0.f, 0.f};
    f32x4 acc[4][8];
#pragma unroll
    for (int i = 0; i < 4; ++i)
#pragma unroll
        for (int j = 0; j < 8; ++j) acc[i][j] = fzero;

    for (int kt = 0; kt < 16; ++kt) {
        int k0 = kt * 32;
        __syncthreads();
        // A staging: WfB [256][512] rows m, async 16 B/lane, 4 issues
#pragma unroll
        for (int q = 0; q < 4; ++q) {
            int row = q * 64 + (t >> 2);
            async_copy16(At + (size_t)q * 2048 + (size_t)t * 8,
                         WfB + (size_t)row * K_ + k0 + (t & 3) * 8);
        }
        if (kt < 8) {
            // B staging, img half: gather+blend 8 ch per task
#pragma unroll
            for (int pass = 0; pass < 2; ++pass) {
                int tau = pass * 256 + t;
                int pt = tau >> 2, cg = tau & 3;
                uint4 o4 = offs4[pt];
                float4 w4 = wts4[pt];
                int ch = k0 + cg * 8;
                uint4 cA = *(const uint4*)(imb + (size_t)o4.x * 256 + ch);
                uint4 cB = *(const uint4*)(imb + (size_t)o4.y * 256 + ch);
                uint4 cC = *(const uint4*)(imb + (size_t)o4.z * 256 + ch);
                uint4 cD = *(const uint4*)(imb + (size_t)o4.w * 256 + ch);
                const unsigned short* pa = (const unsigned short*)&cA;
                const unsigned short* pb = (const unsigned short*)&cB;
                const unsigned short* pc = (const unsigned short*)&cC;
                const unsigned short* pd = (const unsigned short*)&cD;
                uint4 ov;
                unsigned short* po = (unsigned short*)&ov;
#pragma unroll
                for (int e = 0; e < 8; ++e)
                    po[e] = f2bf(w4.x * bf2f(pa[e]) + w4.y * bf2f(pb[e]) +
                                 w4.z * bf2f(pc[e]) + w4.w * bf2f(pd[e]));
                *(uint4*)(Bt + pt * 40 + cg * 8) = ov;
            }
        } else {
            // B staging, pts half: fp32 coalesced load + LDS transpose
            int c_local = t & 31, g = t >> 5;
            int c = (kt - 8) * 32 + c_local;
            const float* src = pts + ((size_t)bb * 256 + c) * (size_t)N_ + n0 + g * 16;
            float4 v0 = *(const float4*)(src + 0);
            float4 v1 = *(const float4*)(src + 4);
            float4 v2 = *(const float4*)(src + 8);
            float4 v3 = *(const float4*)(src + 12);
            unsigned short* dst = Bt + (size_t)g * 16 * 40 + c_local;
            dst[0 * 40] = f2bf(v0.x); dst[1 * 40] = f2bf(v0.y);
            dst[2 * 40] = f2bf(v0.z); dst[3 * 40] = f2bf(v0.w);
            dst[4 * 40] = f2bf(v1.x); dst[5 * 40] = f2bf(v1.y);
            dst[6 * 40] = f2bf(v1.z); dst[7 * 40] = f2bf(v1.w);
            dst[8 * 40] = f2bf(v2.x); dst[9 * 40] = f2bf(v2.y);
            dst[10 * 40] = f2bf(v2.z); dst[11 * 40] = f2bf(v2.w);
            dst[12 * 40] = f2bf(v3.x); dst[13 * 40] = f2bf(v3.y);
            dst[14 * 40] = f2bf(v3.z); dst[15 * 40] = f2bf(v3.w);
        }
        __syncthreads();
        bf16x8 af[4], bv[8];
#pragma unroll
        for (int j = 0; j < 8; ++j)
            bv[j] = *(const bf16x8*)(Bt + (j * 16 + l15) * 40 + quad * 8);
#pragma unroll
        for (int i = 0; i < 4; ++i)
            af[i] = *(const bf16x8*)(At + (w * 64 + i * 16 + l15) * 32 + quad * 8);
#pragma unroll
        for (int i = 0; i < 4; ++i)
#pragma unroll
            for (int j = 0; j < 8; ++j)
                acc[i][j] = __builtin_amdgcn_mfma_f32_16x16x32_bf16(af[i], bv[j], acc[i][j], 0, 0, 0);
    }

    // ---- epilogue: bias, BN stats, LDS-tiled coalesced Y stores
    __syncthreads();
    biasS[t] = fb[t];
    __syncthreads();
    // BN stats from fp32 accs (+bias): sum over 8 j in-thread, 16 l15 via shfl
#pragma unroll
    for (int i = 0; i < 4; ++i) {
        int mq = w * 64 + i * 16 + quad * 4;
#pragma unroll
        for (int r = 0; r < 4; ++r) {
            float bia = biasS[mq + r];
            float s = 0.f, q = 0.f;
#pragma unroll
            for (int j = 0; j < 8; ++j) {
                float y = acc[i][j][r] + bia;
                s += y; q += y * y;
            }
#pragma unroll
            for (int d = 1; d < 16; d <<= 1) {
                s += __shfl_xor(s, d, 64);
                q += __shfl_xor(q, d, 64);
            }
            if (l15 == 0) { redS[mq + r] = s; redQ[mq + r] = q; }
        }
    }
    size_t Yrow0 = ((size_t)bb * N_ + n0) * 256;
#pragma unroll
    for (int h = 0; h < 2; ++h) {
        if (h == 1) __syncthreads();
        if ((w >> 1) == h) {
            int hw = w & 1;
#pragma unroll
            for (int i = 0; i < 4; ++i) {
                int mloc = hw * 64 + i * 16 + quad * 4;
                int mg = h * 128 + mloc;
                float b0 = biasS[mg + 0], b1 = biasS[mg + 1];
                float b2 = biasS[mg + 2], b3 = biasS[mg + 3];
#pragma unroll
                for (int j = 0; j < 8; ++j) {
                    int n = j * 16 + l15;
                    ushort4 o;
                    o.x = f2bf(acc[i][j][0] + b0);
                    o.y = f2bf(acc[i][j][1] + b1);
                    o.z = f2bf(acc[i][j][2] + b2);
                    o.w = f2bf(acc[i][j][3] + b3);
                    *(ushort4*)(tile + n * 136 + mloc) = o;
                }
            }
        }
        __syncthreads();
        if (h == 0) {
            float* bk = buckets + (size_t)(blockIdx.x & 15) * 512;
            atomicAdd(bk + t, redS[t]);
            atomicAdd(bk + 256 + t, redQ[t]);
        }
#pragma unroll
        for (int pass = 0; pass < 8; ++pass) {
            int row = pass * 16 + (t >> 4);
            int cB = (t & 15) * 8;
            uint4 v = *(const uint4*)(tile + row * 136 + cB);
            *(uint4*)(Y + Yrow0 + (size_t)row * 256 + h * 128 + cB) = v;
        }
    }
}

// ---- fused gate (unchanged from R4)
__global__ __launch_bounds__(256, 2) void k_gate(const unsigned short* __restrict__ Y,
                                                 const float* __restrict__ buckets,
                                                 const float* __restrict__ gamma,
                                                 const float* __restrict__ beta,
                                                 const unsigned short* __restrict__ saB,
                                                 const float* __restrict__ sab,
                                                 const unsigned short* __restrict__ c1B,
                                                 const float* __restrict__ c1b,
                                                 const unsigned short* __restrict__ c2B,
                                                 unsigned int* __restrict__ camax,
                                                 float* __restrict__ sp_g,
                                                 float* __restrict__ ss_out) {
    __shared__ __align__(16) unsigned short Ft[64 * 264];
    __shared__ __align__(16) unsigned short Ht[64 * 72];
    __shared__ float scS[256], shS[256];
    __shared__ float saPart[4][64];
    __shared__ float spL[64];
    int t = threadIdx.x;
    size_t pts0 = (size_t)blockIdx.x * 64;
    int b = (int)(pts0 >> 14);
    int w = t >> 6, lane = t & 63, quad = lane >> 4, l15 = lane & 15;
    int jrow = w * 16 + l15;

    bf16x8 bvs[8], bvc[8];
#pragma unroll
    for (int kt = 0; kt < 8; ++kt) {
        bvs[kt] = *(const bf16x8*)(saB + (size_t)jrow * 256 + kt * 32 + quad * 8);
        bvc[kt] = *(const bf16x8*)(c1B + (size_t)jrow * 256 + kt * 32 + quad * 8);
    }
    float sbias = sab[jrow];
    float cbias = c1b[jrow];

    {
        float s = 0.f, q = 0.f;
#pragma unroll
        for (int bk = 0; bk < 16; ++bk) {
            s += buckets[bk * 512 + t];
            q += buckets[bk * 512 + 256 + t];
        }
        const float inv = 1.0f / (float)(B_ * N_);
        float mean = s * inv;
        float var = q * inv - mean * mean;
        float sc = gamma[t] * rsqrtf(var + 1e-5f);
        float sh = beta[t] - mean * sc;
        scS[t] = sc;
        shS[t] = sh;
        if (blockIdx.x == 0) { ss_out[t] = sc; ss_out[256 + t] = sh; }
    }
    __syncthreads();

    int cc = (t * 8) & 255;
    float scr[8], shr[8];
#pragma unroll
    for (int e = 0; e < 8; ++e) { scr[e] = scS[cc + e]; shr[e] = shS[cc + e]; }
    for (int idx = t * 8; idx < 64 * 256; idx += 2048) {
        int r = idx >> 8;
        uint4 v = *(const uint4*)(Y + (pts0 + r) * 256 + cc);
        unsigned short* us = (unsigned short*)&v;
#pragma unroll
        for (int e = 0; e < 8; ++e) {
            float f = bf2f(us[e]) * scr[e] + shr[e];
            us[e] = f2bf(fmaxf(f, 0.f));
        }
        *(uint4*)(Ft + r * 264 + cc) = v;
    }
    __syncthreads();

    const f32x4 fzero = {0.f, 0.f, 0.f, 0.f};
    f32x4 accS[4], accC[4];
#pragma unroll
    for (int i = 0; i < 4; ++i) { accS[i] = fzero; accC[i] = fzero; }
#pragma unroll
    for (int kt = 0; kt < 8; ++kt) {
        bf16x8 af[4];
#pragma unroll
        for (int i = 0; i < 4; ++i)
            af[i] = *(const bf16x8*)(Ft + (i * 16 + l15) * 264 + kt * 32 + quad * 8);
#pragma unroll
        for (int i = 0; i < 4; ++i) {
            accS[i] = __builtin_amdgcn_mfma_f32_16x16x32_bf16(af[i], bvs[kt], accS[i], 0, 0, 0);
            accC[i] = __builtin_amdgcn_mfma_f32_16x16x32_bf16(af[i], bvc[kt], accC[i], 0, 0, 0);
        }
    }
#pragma unroll
    for (int i = 0; i < 4; ++i) {
#pragma unroll
        for (int r = 0; r < 4; ++r) {
            float v = accS[i][r] + sbias;
#pragma unroll
            for (int d = 1; d < 16; d <<= 1) v = fmaxf(v, __shfl_xor(v, d, 64));
            if (l15 == 0) saPart[w][i * 16 + quad * 4 + r] = v;
        }
    }
    __syncthreads();
    if (t < 64) {
        float m4 = fmaxf(fmaxf(saPart[0][t], saPart[1][t]),
                         fmaxf(saPart[2][t], saPart[3][t]));
        float sv = 1.0f / (1.0f + __expf(-m4));
        spL[t] = sv;
        sp_g[pts0 + t] = sv;
    }
    __syncthreads();

#pragma unroll
    for (int i = 0; i < 4; ++i) {
#pragma unroll
        for (int r = 0; r < 4; ++r) {
            int pt = i * 16 + quad * 4 + r;
            float hv = fmaxf(accC[i][r] * spL[pt] + cbias, 0.f);
            Ht[pt * 72 + jrow] = f2bf(hv);
        }
    }
    __syncthreads();

    {
        bf16x8 b2a[4], b2b[4];
#pragma unroll
        for (int mt = 0; mt < 4; ++mt) {
            b2a[mt] = *(const bf16x8*)(c2B + (size_t)(w * 64 + mt * 16 + l15) * 64 + quad * 8);
            b2b[mt] = *(const bf16x8*)(c2B + (size_t)(w * 64 + mt * 16 + l15) * 64 + 32 + quad * 8);
        }
        float vmax[4] = {-3e38f, -3e38f, -3e38f, -3e38f};
#pragma unroll
        for (int i = 0; i < 4; ++i) {
            bf16x8 a0 = *(const bf16x8*)(Ht + (i * 16 + l15) * 72 + quad * 8);
            bf16x8 a1 = *(const bf16x8*)(Ht + (i * 16 + l15) * 72 + 32 + quad * 8);
#pragma unroll
            for (int mt = 0; mt < 4; ++mt) {
                f32x4 acc = __builtin_amdgcn_mfma_f32_16x16x32_bf16(a0, b2a[mt], fzero, 0, 0, 0);
                acc = __builtin_amdgcn_mfma_f32_16x16x32_bf16(a1, b2b[mt], acc, 0, 0, 0);
#pragma unroll
                for (int r = 0; r < 4; ++r) vmax[mt] = fmaxf(vmax[mt], acc[r]);
            }
        }
        unsigned int* cam = camax + (size_t)(blockIdx.x & 7) * 1024 + b * 256;
#pragma unroll
        for (int mt = 0; mt < 4; ++mt) {
            float v = vmax[mt];
            v = fmaxf(v, __shfl_xor(v, 16, 64));
            v = fmaxf(v, __shfl_xor(v, 32, 64));
            if (quad == 0) atomicMax(cam + w * 64 + mt * 16 + l15, fkey(v));
        }
    }
}

// ---- out (unchanged from R4)
__global__ __launch_bounds__(256) void k_out(const unsigned short* __restrict__ Y,
                                             const unsigned int* __restrict__ camax,
                                             const float* __restrict__ c2b,
                                             const float* __restrict__ ss,
                                             const float* __restrict__ sp_g,
                                             float* __restrict__ out) {
    __shared__ __align__(16) unsigned short tile[64 * 68];
    __shared__ float ch[64], scT[64], shT[64], spT[64];
    int t = threadIdx.x;
    int n0 = blockIdx.x * 64, m0 = blockIdx.y * 64, b = blockIdx.z;
    if (t < 64) {
        int m = m0 + t;
        unsigned int k = 0u;
#pragma unroll
        for (int bk = 0; bk < 8; ++bk) k = max(k, camax[bk * 1024 + b * 256 + m]);
        ch[t] = 1.0f / (1.0f + __expf(-(funkey(k) + c2b[m])));
        scT[t] = ss[m];
        shT[t] = ss[256 + m];
        spT[t] = sp_g[(size_t)b * N_ + n0 + t];
    }
    int sub = (t & 15) * 4, grp = t >> 4;
    const unsigned short* src = Y + ((size_t)b * N_ + n0) * 256 + m0;
#pragma unroll
    for (int it = 0; it < 4; ++it) {
        int nl = grp + it * 16;
        ushort4 v = *(const ushort4*)(src + (size_t)nl * 256 + sub);
        *(ushort4*)(tile + nl * 68 + sub) = v;
    }
    __syncthreads();
    float* dst = out + ((size_t)b * 256 + m0) * N_ + n0;
#pragma unroll
    for (int it = 0; it < 4; ++it) {
        int ml = grp + it * 16;
        float g = ch[ml], scv = scT[ml], shv = shT[ml];
        float4 o;
        o.x = fmaxf(bf2f(tile[(sub + 0) * 68 + ml]) * scv + shv, 0.f) * spT[sub + 0] * g;
        o.y = fmaxf(bf2f(tile[(sub + 1) * 68 + ml]) * scv + shv, 0.f) * spT[sub + 1] * g;
        o.z = fmaxf(bf2f(tile[(sub + 2) * 68 + ml]) * scv + shv, 0.f) * spT[sub + 2] * g;
        o.w = fmaxf(bf2f(tile[(sub + 3) * 68 + ml]) * scv + shv, 0.f) * spT[sub + 3] * g;
        *(float4*)(dst + (size_t)ml * N_ + sub) = o;
    }
}

extern "C" void kernel_launch(void* const* d_in, const int* in_sizes, int n_in,
                              void* d_out, int out_size, void* d_ws, size_t ws_size,
                              hipStream_t stream) {
    (void)in_sizes; (void)n_in; (void)out_size; (void)ws_size;
    const float* pts_img = (const float*)d_in[0];
    const float* img     = (const float*)d_in[1];
    const float* pts     = (const float*)d_in[2];
    const float* fw      = (const float*)d_in[3];
    const float* fbias   = (const float*)d_in[4];
    const float* gamma   = (const float*)d_in[5];
    const float* beta    = (const float*)d_in[6];
    const float* c1w     = (const float*)d_in[7];
    const float* c1b     = (const float*)d_in[8];
    const float* c2w     = (const float*)d_in[9];
    const float* c2b     = (const float*)d_in[10];
    const float* saw     = (const float*)d_in[11];
    const float* sab     = (const float*)d_in[12];
    float* out = (float*)d_out;

    char* ws = (char*)d_ws;
    unsigned short* imgT = (unsigned short*)(ws);              // 20,971,520 B
    unsigned short* Y    = (unsigned short*)(ws + 20971520);   // 33,554,432 B
    unsigned short* WfB  = (unsigned short*)(ws + 54525952);   // 262,144 B
    unsigned short* saB  = (unsigned short*)(ws + 54788096);   // 32,768 B
    unsigned short* ca1B = (unsigned short*)(ws + 54820864);   // 32,768 B
    unsigned short* ca2B = (unsigned short*)(ws + 54853632);   // 32,768 B
    float* buckets       = (float*)(ws + 54886400);            // 32,768 B
    unsigned int* camax  = (unsigned int*)(ws + 54919168);     // 32,768 B
    float* sp_g          = (float*)(ws + 54951936);            // 262,144 B
    float* ss            = (float*)(ws + 55214080);            // 2,048 B

    k_imgt<<<3264, 256, 0, stream>>>(img, imgT, fw, saw, c1w, c2w,
                                     WfB, saB, ca1B, ca2B, buckets, camax);
    k_gemm1f<<<dim3(128, 4), 256, 0, stream>>>(WfB, pts_img, imgT, pts, fbias, Y, buckets);
    k_gate<<<1024, 256, 0, stream>>>(Y, buckets, gamma, beta, saB, sab, ca1B, c1b,
                                     ca2B, camax, sp_g, ss);
    k_out<<<dim3(256, 4, 4), 256, 0, stream>>>(Y, camax, c2b, ss, sp_g, out);
}